// Round 1
// baseline (2104.495 us; speedup 1.0000x reference)
//
#include <hip/hip_runtime.h>

typedef __attribute__((ext_vector_type(4))) float f32x4;
typedef __attribute__((ext_vector_type(8))) _Float16 f16x8;

#define NSRC 8192
#define MANC 4096
#define QDIM 4096
#define VDIM 512
#define DM   1024
#define FFD  2048

__device__ __forceinline__ ushort f2h(float f){ _Float16 h=(_Float16)f; return __builtin_bit_cast(ushort,h); }
__device__ __forceinline__ uint pk2(float a,float b){ return (uint)f2h(a) | ((uint)f2h(b)<<16); }

// ---------- f32 -> f16 convert, 8 elems/thread ----------
__global__ __launch_bounds__(256) void k_conv(const float* __restrict__ in, ushort* __restrict__ out, long n){
  long i = ((long)blockIdx.x*256 + threadIdx.x)*8;
  if (i >= n) return;
  float4 a = *(const float4*)(in+i);
  float4 b = *(const float4*)(in+i+4);
  uint4 o; o.x=pk2(a.x,a.y); o.y=pk2(a.z,a.w); o.z=pk2(b.x,b.y); o.w=pk2(b.z,b.w);
  *(uint4*)(out+i) = o;
}

// ---------- W[K][N] f32 -> WT[N][K] f16 ----------
__global__ __launch_bounds__(256) void k_transpose(const float* __restrict__ W, ushort* __restrict__ WT, int K, int N){
  __shared__ float tile[32][33];
  int n0 = blockIdx.x*32, k0 = blockIdx.y*32;
  int tx = threadIdx.x & 31, ty = threadIdx.x >> 5;
  #pragma unroll
  for (int i=0;i<4;++i) tile[ty+i*8][tx] = W[(long)(k0+ty+i*8)*N + n0+tx];
  __syncthreads();
  #pragma unroll
  for (int i=0;i<4;++i){ int nn=ty+i*8; WT[(long)(n0+nn)*K + k0+tx] = f2h(tile[tx][nn]); }
}

// ---------- generic f16 GEMM: C[M,N] = A[M,K] * Bt[N,K]^T ----------
// EPI: 0 f16 out +bias | 1 f16 out transposed +bias | 2 f32 out *alpha*extra |
//      3 f32 out *alpha | 4 f16 out tanh(+bias) | 5 f32 out +bias+extra | 6 f32 out +bias
template<int EPI>
__global__ __launch_bounds__(256) void k_gemm(const ushort* __restrict__ A, const ushort* __restrict__ Bt,
    int M, int N, int K, const float* __restrict__ bias, const float* __restrict__ extra,
    float alpha, float* __restrict__ Cf, ushort* __restrict__ Ch)
{
  __shared__ ushort As[128*64];
  __shared__ ushort Bs[128*64];
  const int tid = threadIdx.x, lane = tid & 63, w = tid>>6;
  const int wm = (w>>1)*64, wn = (w&1)*64;
  const int m0 = blockIdx.y*128, n0 = blockIdx.x*128;
  const int lr = lane & 15, kg = lane >> 4;
  f32x4 acc[4][4] = {};
  const int nkt = K >> 6;
  uint4 pa[4], pb[4];
  const ushort* Ap = A + (long)m0*K;
  const ushort* Bp = Bt + (long)n0*K;
  #pragma unroll
  for (int j=0;j<4;++j){
    int chunk = tid + j*256, row = chunk>>3, c = chunk&7;
    pa[j] = *(const uint4*)(Ap + (long)row*K + c*8);
    pb[j] = *(const uint4*)(Bp + (long)row*K + c*8);
  }
  for (int kt=0; kt<nkt; ++kt){
    __syncthreads();
    #pragma unroll
    for (int j=0;j<4;++j){
      int chunk = tid + j*256, row = chunk>>3, c = chunk&7;
      *(uint4*)&As[row*64 + ((c ^ (row&7))*8)] = pa[j];
      *(uint4*)&Bs[row*64 + ((c ^ (row&7))*8)] = pb[j];
    }
    __syncthreads();
    if (kt+1 < nkt){
      long koff = (long)(kt+1)*64;
      #pragma unroll
      for (int j=0;j<4;++j){
        int chunk = tid + j*256, row = chunk>>3, c = chunk&7;
        pa[j] = *(const uint4*)(Ap + (long)row*K + koff + c*8);
        pb[j] = *(const uint4*)(Bp + (long)row*K + koff + c*8);
      }
    }
    #pragma unroll
    for (int ks=0; ks<2; ++ks){
      f16x8 af[4], bfr[4];
      #pragma unroll
      for (int mi=0;mi<4;++mi){
        int r = wm + mi*16 + lr, c = ks*4 + kg;
        af[mi] = *(const f16x8*)&As[r*64 + ((c ^ (r&7))*8)];
      }
      #pragma unroll
      for (int ni=0;ni<4;++ni){
        int r = wn + ni*16 + lr, c = ks*4 + kg;
        bfr[ni] = *(const f16x8*)&Bs[r*64 + ((c ^ (r&7))*8)];
      }
      #pragma unroll
      for (int mi=0;mi<4;++mi)
        #pragma unroll
        for (int ni=0;ni<4;++ni)
          acc[mi][ni] = __builtin_amdgcn_mfma_f32_16x16x32_f16(af[mi], bfr[ni], acc[mi][ni], 0,0,0);
    }
  }
  #pragma unroll
  for (int mi=0;mi<4;++mi){
    #pragma unroll
    for (int ni=0;ni<4;++ni){
      int col = n0 + wn + ni*16 + lr;
      float bcol = (EPI==2||EPI==3) ? 0.f : bias[col];
      #pragma unroll
      for (int r=0;r<4;++r){
        int row = m0 + wm + mi*16 + kg*4 + r;
        float v = acc[mi][ni][r];
        if (EPI==0)      Ch[(long)row*N + col] = f2h(v + bcol);
        else if (EPI==1) Ch[(long)col*M + row] = f2h(v + bcol);
        else if (EPI==2) Cf[(long)row*N + col] = v*alpha*extra[(long)row*N + col];
        else if (EPI==3) Cf[(long)row*N + col] = v*alpha;
        else if (EPI==4) Ch[(long)row*N + col] = f2h(tanhf(v + bcol));
        else if (EPI==5) Cf[(long)row*N + col] = v + bcol + extra[(long)row*N + col];
        else             Cf[(long)row*N + col] = v + bcol;
      }
    }
  }
}

// ---------- row softmax over 4096 cols, writes prob*512 as f16 ----------
__global__ __launch_bounds__(256) void k_softmax(const float* __restrict__ S, ushort* __restrict__ P){
  const long base = (long)blockIdx.x * 4096;
  const int t = threadIdx.x;
  float4 v[4];
  float mx = -3.4e38f;
  #pragma unroll
  for (int c=0;c<4;++c){
    v[c] = *(const float4*)(S + base + c*1024 + t*4);
    mx = fmaxf(mx, fmaxf(fmaxf(v[c].x,v[c].y), fmaxf(v[c].z,v[c].w)));
  }
  #pragma unroll
  for (int off=1; off<64; off<<=1) mx = fmaxf(mx, __shfl_xor(mx, off));
  __shared__ float red[8];
  int wv = t>>6;
  if ((t&63)==0) red[wv]=mx;
  __syncthreads();
  mx = fmaxf(fmaxf(red[0],red[1]), fmaxf(red[2],red[3]));
  float e[16]; float sum=0.f;
  #pragma unroll
  for (int c=0;c<4;++c){
    e[c*4+0]=__expf(v[c].x-mx); e[c*4+1]=__expf(v[c].y-mx);
    e[c*4+2]=__expf(v[c].z-mx); e[c*4+3]=__expf(v[c].w-mx);
    sum += e[c*4]+e[c*4+1]+e[c*4+2]+e[c*4+3];
  }
  #pragma unroll
  for (int off=1; off<64; off<<=1) sum += __shfl_xor(sum, off);
  if ((t&63)==0) red[4+wv]=sum;
  __syncthreads();
  sum = red[4]+red[5]+red[6]+red[7];
  float s = 512.f/sum;   // x512 scaling keeps tiny probs in f16-normal range
  #pragma unroll
  for (int c=0;c<4;++c){
    ushort4 o; o.x=f2h(e[c*4]*s); o.y=f2h(e[c*4+1]*s); o.z=f2h(e[c*4+2]*s); o.w=f2h(e[c*4+3]*s);
    *(ushort4*)(P + base + c*1024 + t*4) = o;
  }
}

// ---------- batchnorm: partial sums / finalize / apply ----------
__global__ __launch_bounds__(256) void k_bn_partial(const float* __restrict__ X, float* __restrict__ ps, float* __restrict__ pq, int F, int rowsPer){
  int col = blockIdx.x*256 + threadIdx.x;
  long r0 = (long)blockIdx.y * rowsPer;
  float s=0.f,q=0.f;
  for (int r=0;r<rowsPer;++r){ float x = X[(r0+r)*F + col]; s+=x; q+=x*x; }
  ps[(long)blockIdx.y*F + col]=s; pq[(long)blockIdx.y*F + col]=q;
}
__global__ __launch_bounds__(256) void k_bn_final(const float* __restrict__ ps, const float* __restrict__ pq,
    const float* __restrict__ gamma, const float* __restrict__ beta,
    float* __restrict__ scale, float* __restrict__ shift, int F, float invN, int nch){
  int c = blockIdx.x*256 + threadIdx.x;
  if (c>=F) return;
  float s=0.f,q=0.f;
  for (int i=0;i<nch;++i){ s+=ps[i*F+c]; q+=pq[i*F+c]; }
  float mu = s*invN, var = q*invN - mu*mu;
  float sc = gamma[c]*rsqrtf(var+1e-5f);
  scale[c]=sc; shift[c]=beta[c]-mu*sc;
}
__global__ __launch_bounds__(256) void k_bn_apply(const float* __restrict__ X, const float* __restrict__ scale, const float* __restrict__ shift,
    float* __restrict__ Xn, ushort* __restrict__ Xh, int F, long n){
  long i = ((long)blockIdx.x*256 + threadIdx.x)*4;
  if (i>=n) return;
  int c = (int)(i & (long)(F-1));
  float4 x = *(const float4*)(X+i);
  float4 y; y.x=x.x*scale[c]+shift[c]; y.y=x.y*scale[c+1]+shift[c+1];
  y.z=x.z*scale[c+2]+shift[c+2]; y.w=x.w*scale[c+3]+shift[c+3];
  if (Xn) *(float4*)(Xn+i)=y;
  ushort4 o; o.x=f2h(y.x); o.y=f2h(y.y); o.z=f2h(y.z); o.w=f2h(y.w);
  *(ushort4*)(Xh+i)=o;
}
__global__ __launch_bounds__(256) void k_bn_tanh(const float* __restrict__ X, const float* __restrict__ scale, const float* __restrict__ shift,
    float* __restrict__ O, int F, long n){
  long i = ((long)blockIdx.x*256 + threadIdx.x)*4;
  if (i>=n) return;
  int c = (int)(i & (long)(F-1));
  float4 x = *(const float4*)(X+i);
  float4 y; y.x=tanhf(x.x*scale[c]+shift[c]); y.y=tanhf(x.y*scale[c+1]+shift[c+1]);
  y.z=tanhf(x.z*scale[c+2]+shift[c+2]); y.w=tanhf(x.w*scale[c+3]+shift[c+3]);
  *(float4*)(O+i)=y;
}

extern "C" void kernel_launch(void* const* d_in, const int* in_sizes, int n_in,
                              void* d_out, int out_size, void* d_ws, size_t ws_size,
                              hipStream_t stream){
  const float* src = (const float*)d_in[0];
  const float* a1  = (const float*)d_in[1];
  const float* a2  = (const float*)d_in[2];
  const float* lg  = (const float*)d_in[3];
  const float* Wq  = (const float*)d_in[4];
  const float* bq  = (const float*)d_in[5];
  const float* Wv  = (const float*)d_in[6];
  const float* bv  = (const float*)d_in[7];
  const float* W1  = (const float*)d_in[8];
  const float* b1  = (const float*)d_in[9];
  const float* W2  = (const float*)d_in[10];
  const float* b2  = (const float*)d_in[11];
  const float* g1  = (const float*)d_in[12];
  const float* be1 = (const float*)d_in[13];
  const float* g2  = (const float*)d_in[14];
  const float* be2 = (const float*)d_in[15];
  const float* Wd  = (const float*)d_in[16];
  const float* bd  = (const float*)d_in[17];
  const float* gd  = (const float*)d_in[18];
  const float* bed = (const float*)d_in[19];
  char* ws = (char*)d_ws;
  // region R0 (lifetime-aliased)
  ushort* src_h = (ushort*)(ws + 0);
  ushort* a1_h  = (ushort*)(ws + 67108864);
  ushort* a2_h  = (ushort*)(ws + 100663296);
  float*  scores= (float*) (ws + 0);          // after QKV gemms
  float*  x_att = (float*) (ws + 0);          // after softmax
  float*  xn    = (float*) (ws + 33554432);
  ushort* xnb   = (ushort*)(ws + 67108864);
  ushort* hbuf  = (ushort*)(ws + 83886080);
  // region R1 (lifetime-aliased)
  ushort* prob  = (ushort*)(ws + 134217728);
  float*  x2    = (float*) (ws + 134217728);  // after PV
  ushort* x2nb  = (ushort*)(ws + 167772160);
  float*  y     = (float*) (ws + 184549376);
  // persistent
  ushort* Qh    = (ushort*)(ws + 201326592);
  ushort* Kh    = (ushort*)(ws + 218103808);
  ushort* VTh   = (ushort*)(ws + 226492416);
  ushort* WqT   = (ushort*)(ws + 234881024);
  ushort* WvT   = (ushort*)(ws + 243269632);
  ushort* W1T   = (ushort*)(ws + 244318208);
  ushort* W2T   = (ushort*)(ws + 248512512);
  ushort* WdT   = (ushort*)(ws + 252706816);
  float*  ps    = (float*) (ws + 253755392);
  float*  pq    = (float*) (ws + 253886464);
  float*  sc1   = (float*) (ws + 254017536);
  float*  sh1   = (float*) (ws + 254021632);
  float*  sc2   = (float*) (ws + 254025728);
  float*  sh2   = (float*) (ws + 254029824);
  float*  scd   = (float*) (ws + 254033920);
  float*  shd   = (float*) (ws + 254035968);

  dim3 b256(256);
  // conversions + weight transposes
  k_conv<<<dim3(16384), b256, 0, stream>>>(src, src_h, (long)NSRC*QDIM);
  k_conv<<<dim3(8192),  b256, 0, stream>>>(a1, a1_h, (long)MANC*QDIM);
  k_conv<<<dim3(1024),  b256, 0, stream>>>(a2, a2_h, (long)MANC*VDIM);
  k_transpose<<<dim3(DM/32, QDIM/32), b256, 0, stream>>>(Wq, WqT, QDIM, DM);
  k_transpose<<<dim3(DM/32, VDIM/32), b256, 0, stream>>>(Wv, WvT, VDIM, DM);
  k_transpose<<<dim3(FFD/32, DM/32),  b256, 0, stream>>>(W1, W1T, DM, FFD);
  k_transpose<<<dim3(DM/32, FFD/32),  b256, 0, stream>>>(W2, W2T, FFD, DM);
  k_transpose<<<dim3(VDIM/32, DM/32), b256, 0, stream>>>(Wd, WdT, DM, VDIM);
  // Q, K, V^T
  k_gemm<0><<<dim3(DM/128, NSRC/128), b256, 0, stream>>>(src_h, WqT, NSRC, DM, QDIM, bq, nullptr, 1.f, nullptr, Qh);
  k_gemm<0><<<dim3(DM/128, MANC/128), b256, 0, stream>>>(a1_h, WqT, MANC, DM, QDIM, bq, nullptr, 1.f, nullptr, Kh);
  k_gemm<1><<<dim3(DM/128, MANC/128), b256, 0, stream>>>(a2_h, WvT, MANC, DM, VDIM, bv, nullptr, 1.f, nullptr, VTh);
  // scores = (Q K^T)/32 * label_graph ; softmax ; x = prob V
  k_gemm<2><<<dim3(MANC/128, NSRC/128), b256, 0, stream>>>(Qh, Kh, NSRC, MANC, DM, nullptr, lg, 0.03125f, scores, nullptr);
  k_softmax<<<dim3(NSRC), b256, 0, stream>>>(scores, prob);
  k_gemm<3><<<dim3(DM/128, NSRC/128), b256, 0, stream>>>(prob, VTh, NSRC, DM, MANC, nullptr, nullptr, 1.f/512.f, x_att, nullptr);
  // BN1
  k_bn_partial<<<dim3(DM/256, 32), b256, 0, stream>>>(x_att, ps, pq, DM, NSRC/32);
  k_bn_final<<<dim3(DM/256), b256, 0, stream>>>(ps, pq, g1, be1, sc1, sh1, DM, 1.f/NSRC, 32);
  k_bn_apply<<<dim3(8192), b256, 0, stream>>>(x_att, sc1, sh1, xn, xnb, DM, (long)NSRC*DM);
  // FFN
  k_gemm<4><<<dim3(FFD/128, NSRC/128), b256, 0, stream>>>(xnb, W1T, NSRC, FFD, DM, b1, nullptr, 1.f, nullptr, hbuf);
  k_gemm<5><<<dim3(DM/128, NSRC/128), b256, 0, stream>>>(hbuf, W2T, NSRC, DM, FFD, b2, xn, 1.f, x2, nullptr);
  // BN2
  k_bn_partial<<<dim3(DM/256, 32), b256, 0, stream>>>(x2, ps, pq, DM, NSRC/32);
  k_bn_final<<<dim3(DM/256), b256, 0, stream>>>(ps, pq, g2, be2, sc2, sh2, DM, 1.f/NSRC, 32);
  k_bn_apply<<<dim3(8192), b256, 0, stream>>>(x2, sc2, sh2, nullptr, x2nb, DM, (long)NSRC*DM);
  // decoder + BN + tanh
  k_gemm<6><<<dim3(VDIM/128, NSRC/128), b256, 0, stream>>>(x2nb, WdT, NSRC, VDIM, DM, bd, nullptr, 1.f, y, nullptr);
  k_bn_partial<<<dim3(VDIM/256, 32), b256, 0, stream>>>(y, ps, pq, VDIM, NSRC/32);
  k_bn_final<<<dim3(2), b256, 0, stream>>>(ps, pq, gd, bed, scd, shd, VDIM, 1.f/NSRC, 32);
  k_bn_tanh<<<dim3(4096), b256, 0, stream>>>(y, scd, shd, (float*)d_out, VDIM, (long)NSRC*VDIM);
}

// Round 2
// 850.048 us; speedup vs baseline: 2.4757x; 2.4757x over previous
//
#include <hip/hip_runtime.h>

typedef __attribute__((ext_vector_type(4))) float f32x4;
typedef __attribute__((ext_vector_type(8))) _Float16 f16x8;

#define NSRC 8192
#define MANC 4096
#define QDIM 4096
#define VDIM 512
#define DM   1024
#define FFD  2048

__device__ __forceinline__ ushort f2h(float f){ _Float16 h=(_Float16)f; return __builtin_bit_cast(ushort,h); }
__device__ __forceinline__ uint pk2(float a,float b){ return (uint)f2h(a) | ((uint)f2h(b)<<16); }

__device__ __forceinline__ void gload16(const ushort* g, ushort* l){
  __builtin_amdgcn_global_load_lds(
    (const __attribute__((address_space(1))) unsigned int*)g,
    (__attribute__((address_space(3))) unsigned int*)l, 16, 0, 0);
}

// ---------- f32 -> f16 convert, 8 elems/thread ----------
__global__ __launch_bounds__(256) void k_conv(const float* __restrict__ in, ushort* __restrict__ out, long n){
  long i = ((long)blockIdx.x*256 + threadIdx.x)*8;
  if (i >= n) return;
  float4 a = *(const float4*)(in+i);
  float4 b = *(const float4*)(in+i+4);
  uint4 o; o.x=pk2(a.x,a.y); o.y=pk2(a.z,a.w); o.z=pk2(b.x,b.y); o.w=pk2(b.z,b.w);
  *(uint4*)(out+i) = o;
}

// ---------- W[K][N] f32 -> WT[N][K] f16 ----------
__global__ __launch_bounds__(256) void k_transpose(const float* __restrict__ W, ushort* __restrict__ WT, int K, int N){
  __shared__ float tile[32][33];
  int n0 = blockIdx.x*32, k0 = blockIdx.y*32;
  int tx = threadIdx.x & 31, ty = threadIdx.x >> 5;
  #pragma unroll
  for (int i=0;i<4;++i) tile[ty+i*8][tx] = W[(long)(k0+ty+i*8)*N + n0+tx];
  __syncthreads();
  #pragma unroll
  for (int i=0;i<4;++i){ int nn=ty+i*8; WT[(long)(n0+nn)*K + k0+tx] = f2h(tile[tx][nn]); }
}

// ---------- generic f16 GEMM: C[M,N] = A[M,K] * Bt[N,K]^T ----------
// m97-structure: global_load_lds(16B) staging with pre-swizzled source, XOR-swizzled
// LDS reads, XCD-chunked 1D grid swizzle, LDS-transposed coalesced epilogue.
// EPI: 0 f16 out +bias | 1 f16 out transposed +bias | 2 f32 out *alpha*extra |
//      3 f32 out *alpha | 4 f16 out tanh(+bias) | 5 f32 out +bias+extra | 6 f32 out +bias
template<int EPI>
__global__ __launch_bounds__(256,2) void k_gemm(const ushort* __restrict__ A, const ushort* __restrict__ Bt,
    int M, int N, int K, const float* __restrict__ bias, const float* __restrict__ extra,
    float alpha, float* __restrict__ Cf, ushort* __restrict__ Ch, int gxm1, int lg2gx)
{
  __shared__ ushort As[128*64];
  __shared__ ushort Bs[128*64];
  const int tid = threadIdx.x, lane = tid & 63, w = tid>>6;
  const int wm = (w>>1)*64, wn = (w&1)*64;
  // XCD-chunked swizzle: XCD k (= blockIdx%8) owns a contiguous nid band (contig by rows)
  int id = blockIdx.x;
  int nid = (id & 7)*((int)gridDim.x >> 3) + (id >> 3);
  const int m0 = (nid >> lg2gx)*128, n0 = (nid & gxm1)*128;
  const int lr = lane & 15, kg = lane >> 4;
  f32x4 acc[4][4] = {};
  const int nkt = K >> 6;
  const ushort* Ap = A + (long)m0*K;
  const ushort* Bp = Bt + (long)n0*K;
  // staging map: LDS chunk c (16B) at byte c*16 holds global chunk (c&7)^(row&7) of row c>>3
  int rowj[4], colj[4];
  #pragma unroll
  for (int j=0;j<4;++j){
    int c = w*256 + j*64 + lane;
    rowj[j] = c>>3; colj[j] = (c&7) ^ (rowj[j]&7);
  }
  for (int kt=0; kt<nkt; ++kt){
    __syncthreads();                       // prior compute done before overwrite
    long ko = (long)kt*64;
    #pragma unroll
    for (int j=0;j<4;++j){
      gload16(Ap + (long)rowj[j]*K + ko + colj[j]*8, As + (w*4+j)*512);
      gload16(Bp + (long)rowj[j]*K + ko + colj[j]*8, Bs + (w*4+j)*512);
    }
    __syncthreads();                       // compiler drains vmcnt before barrier
    #pragma unroll
    for (int ks=0; ks<2; ++ks){
      f16x8 af[4], bfr[4];
      #pragma unroll
      for (int mi=0;mi<4;++mi){
        int r = wm + mi*16 + lr, c = ks*4 + kg;
        af[mi] = *(const f16x8*)&As[r*64 + ((c ^ (r&7))*8)];
      }
      #pragma unroll
      for (int ni=0;ni<4;++ni){
        int r = wn + ni*16 + lr, c = ks*4 + kg;
        bfr[ni] = *(const f16x8*)&Bs[r*64 + ((c ^ (r&7))*8)];
      }
      #pragma unroll
      for (int mi=0;mi<4;++mi)
        #pragma unroll
        for (int ni=0;ni<4;++ni)
          acc[mi][ni] = __builtin_amdgcn_mfma_f32_16x16x32_f16(af[mi], bfr[ni], acc[mi][ni], 0,0,0);
    }
  }
  // ---- epilogue: transpose 16x64 slices through LDS -> coalesced row-major stores ----
  __syncthreads();
  float* Lw = ((float*)As) + w*1024;       // per-wave 16x64 f32 slice (4 KB)
  #pragma unroll
  for (int mi=0;mi<4;++mi){
    #pragma unroll
    for (int ni=0;ni<4;++ni)
      #pragma unroll
      for (int r=0;r<4;++r)
        Lw[(kg*4+r)*64 + ni*16 + lr] = acc[mi][ni][r];
    __syncthreads();
    #pragma unroll
    for (int t=0;t<4;++t){
      int fi = t*64 + lane;                // float4 index within slice
      int row16 = fi >> 4, c4 = fi & 15;
      float4 v4 = *(float4*)&Lw[row16*64 + c4*4];
      int row = m0 + wm + mi*16 + row16;
      int col = n0 + wn + c4*4;
      if (EPI==0){
        float4 b4 = *(const float4*)&bias[col];
        ushort4 o; o.x=f2h(v4.x+b4.x); o.y=f2h(v4.y+b4.y); o.z=f2h(v4.z+b4.z); o.w=f2h(v4.w+b4.w);
        *(ushort4*)&Ch[(long)row*N + col] = o;
      } else if (EPI==1){
        float4 b4 = *(const float4*)&bias[col];
        Ch[(long)(col+0)*M + row] = f2h(v4.x+b4.x);
        Ch[(long)(col+1)*M + row] = f2h(v4.y+b4.y);
        Ch[(long)(col+2)*M + row] = f2h(v4.z+b4.z);
        Ch[(long)(col+3)*M + row] = f2h(v4.w+b4.w);
      } else if (EPI==2){
        float4 e4 = *(const float4*)&extra[(long)row*N + col];
        float4 o; o.x=v4.x*alpha*e4.x; o.y=v4.y*alpha*e4.y; o.z=v4.z*alpha*e4.z; o.w=v4.w*alpha*e4.w;
        *(float4*)&Cf[(long)row*N + col] = o;
      } else if (EPI==3){
        float4 o; o.x=v4.x*alpha; o.y=v4.y*alpha; o.z=v4.z*alpha; o.w=v4.w*alpha;
        *(float4*)&Cf[(long)row*N + col] = o;
      } else if (EPI==4){
        float4 b4 = *(const float4*)&bias[col];
        ushort4 o; o.x=f2h(tanhf(v4.x+b4.x)); o.y=f2h(tanhf(v4.y+b4.y));
        o.z=f2h(tanhf(v4.z+b4.z)); o.w=f2h(tanhf(v4.w+b4.w));
        *(ushort4*)&Ch[(long)row*N + col] = o;
      } else if (EPI==5){
        float4 b4 = *(const float4*)&bias[col];
        float4 e4 = *(const float4*)&extra[(long)row*N + col];
        float4 o; o.x=v4.x+b4.x+e4.x; o.y=v4.y+b4.y+e4.y; o.z=v4.z+b4.z+e4.z; o.w=v4.w+b4.w+e4.w;
        *(float4*)&Cf[(long)row*N + col] = o;
      } else {
        float4 b4 = *(const float4*)&bias[col];
        float4 o; o.x=v4.x+b4.x; o.y=v4.y+b4.y; o.z=v4.z+b4.z; o.w=v4.w+b4.w;
        *(float4*)&Cf[(long)row*N + col] = o;
      }
    }
    __syncthreads();
  }
}

// ---------- row softmax over 4096 cols, writes prob*512 as f16 ----------
__global__ __launch_bounds__(256) void k_softmax(const float* __restrict__ S, ushort* __restrict__ P){
  const long base = (long)blockIdx.x * 4096;
  const int t = threadIdx.x;
  float4 v[4];
  float mx = -3.4e38f;
  #pragma unroll
  for (int c=0;c<4;++c){
    v[c] = *(const float4*)(S + base + c*1024 + t*4);
    mx = fmaxf(mx, fmaxf(fmaxf(v[c].x,v[c].y), fmaxf(v[c].z,v[c].w)));
  }
  #pragma unroll
  for (int off=1; off<64; off<<=1) mx = fmaxf(mx, __shfl_xor(mx, off));
  __shared__ float red[8];
  int wv = t>>6;
  if ((t&63)==0) red[wv]=mx;
  __syncthreads();
  mx = fmaxf(fmaxf(red[0],red[1]), fmaxf(red[2],red[3]));
  float e[16]; float sum=0.f;
  #pragma unroll
  for (int c=0;c<4;++c){
    e[c*4+0]=__expf(v[c].x-mx); e[c*4+1]=__expf(v[c].y-mx);
    e[c*4+2]=__expf(v[c].z-mx); e[c*4+3]=__expf(v[c].w-mx);
    sum += e[c*4]+e[c*4+1]+e[c*4+2]+e[c*4+3];
  }
  #pragma unroll
  for (int off=1; off<64; off<<=1) sum += __shfl_xor(sum, off);
  if ((t&63)==0) red[4+wv]=sum;
  __syncthreads();
  sum = red[4]+red[5]+red[6]+red[7];
  float s = 512.f/sum;   // x512 scaling keeps tiny probs in f16-normal range
  #pragma unroll
  for (int c=0;c<4;++c){
    ushort4 o; o.x=f2h(e[c*4]*s); o.y=f2h(e[c*4+1]*s); o.z=f2h(e[c*4+2]*s); o.w=f2h(e[c*4+3]*s);
    *(ushort4*)(P + base + c*1024 + t*4) = o;
  }
}

// ---------- batchnorm: partial sums / finalize / apply ----------
__global__ __launch_bounds__(256) void k_bn_partial(const float* __restrict__ X, float* __restrict__ ps, float* __restrict__ pq, int F, int rowsPer){
  int col = blockIdx.x*256 + threadIdx.x;
  long r0 = (long)blockIdx.y * rowsPer;
  float s=0.f,q=0.f;
  for (int r=0;r<rowsPer;++r){ float x = X[(r0+r)*F + col]; s+=x; q+=x*x; }
  ps[(long)blockIdx.y*F + col]=s; pq[(long)blockIdx.y*F + col]=q;
}
__global__ __launch_bounds__(256) void k_bn_final(const float* __restrict__ ps, const float* __restrict__ pq,
    const float* __restrict__ gamma, const float* __restrict__ beta,
    float* __restrict__ scale, float* __restrict__ shift, int F, float invN, int nch){
  int c = blockIdx.x*256 + threadIdx.x;
  if (c>=F) return;
  float s=0.f,q=0.f;
  for (int i=0;i<nch;++i){ s+=ps[i*F+c]; q+=pq[i*F+c]; }
  float mu = s*invN, var = q*invN - mu*mu;
  float sc = gamma[c]*rsqrtf(var+1e-5f);
  scale[c]=sc; shift[c]=beta[c]-mu*sc;
}
__global__ __launch_bounds__(256) void k_bn_apply(const float* __restrict__ X, const float* __restrict__ scale, const float* __restrict__ shift,
    float* __restrict__ Xn, ushort* __restrict__ Xh, int F, long n){
  long i = ((long)blockIdx.x*256 + threadIdx.x)*4;
  if (i>=n) return;
  int c = (int)(i & (long)(F-1));
  float4 x = *(const float4*)(X+i);
  float4 y; y.x=x.x*scale[c]+shift[c]; y.y=x.y*scale[c+1]+shift[c+1];
  y.z=x.z*scale[c+2]+shift[c+2]; y.w=x.w*scale[c+3]+shift[c+3];
  if (Xn) *(float4*)(Xn+i)=y;
  ushort4 o; o.x=f2h(y.x); o.y=f2h(y.y); o.z=f2h(y.z); o.w=f2h(y.w);
  *(ushort4*)(Xh+i)=o;
}
__global__ __launch_bounds__(256) void k_bn_tanh(const float* __restrict__ X, const float* __restrict__ scale, const float* __restrict__ shift,
    float* __restrict__ O, int F, long n){
  long i = ((long)blockIdx.x*256 + threadIdx.x)*4;
  if (i>=n) return;
  int c = (int)(i & (long)(F-1));
  float4 x = *(const float4*)(X+i);
  float4 y; y.x=tanhf(x.x*scale[c]+shift[c]); y.y=tanhf(x.y*scale[c+1]+shift[c+1]);
  y.z=tanhf(x.z*scale[c+2]+shift[c+2]); y.w=tanhf(x.w*scale[c+3]+shift[c+3]);
  *(float4*)(O+i)=y;
}

extern "C" void kernel_launch(void* const* d_in, const int* in_sizes, int n_in,
                              void* d_out, int out_size, void* d_ws, size_t ws_size,
                              hipStream_t stream){
  const float* src = (const float*)d_in[0];
  const float* a1  = (const float*)d_in[1];
  const float* a2  = (const float*)d_in[2];
  const float* lg  = (const float*)d_in[3];
  const float* Wq  = (const float*)d_in[4];
  const float* bq  = (const float*)d_in[5];
  const float* Wv  = (const float*)d_in[6];
  const float* bv  = (const float*)d_in[7];
  const float* W1  = (const float*)d_in[8];
  const float* b1  = (const float*)d_in[9];
  const float* W2  = (const float*)d_in[10];
  const float* b2  = (const float*)d_in[11];
  const float* g1  = (const float*)d_in[12];
  const float* be1 = (const float*)d_in[13];
  const float* g2  = (const float*)d_in[14];
  const float* be2 = (const float*)d_in[15];
  const float* Wd  = (const float*)d_in[16];
  const float* bd  = (const float*)d_in[17];
  const float* gd  = (const float*)d_in[18];
  const float* bed = (const float*)d_in[19];
  char* ws = (char*)d_ws;
  // region R0 (lifetime-aliased)
  ushort* src_h = (ushort*)(ws + 0);
  ushort* a1_h  = (ushort*)(ws + 67108864);
  ushort* a2_h  = (ushort*)(ws + 100663296);
  float*  scores= (float*) (ws + 0);          // after QKV gemms
  float*  x_att = (float*) (ws + 0);          // after softmax
  float*  xn    = (float*) (ws + 33554432);
  ushort* xnb   = (ushort*)(ws + 67108864);
  ushort* hbuf  = (ushort*)(ws + 83886080);
  // region R1 (lifetime-aliased)
  ushort* prob  = (ushort*)(ws + 134217728);
  float*  x2    = (float*) (ws + 134217728);  // after PV
  ushort* x2nb  = (ushort*)(ws + 167772160);
  float*  y     = (float*) (ws + 184549376);
  // persistent
  ushort* Qh    = (ushort*)(ws + 201326592);
  ushort* Kh    = (ushort*)(ws + 218103808);
  ushort* VTh   = (ushort*)(ws + 226492416);
  ushort* WqT   = (ushort*)(ws + 234881024);
  ushort* WvT   = (ushort*)(ws + 243269632);
  ushort* W1T   = (ushort*)(ws + 244318208);
  ushort* W2T   = (ushort*)(ws + 248512512);
  ushort* WdT   = (ushort*)(ws + 252706816);
  float*  ps    = (float*) (ws + 253755392);
  float*  pq    = (float*) (ws + 253886464);
  float*  sc1   = (float*) (ws + 254017536);
  float*  sh1   = (float*) (ws + 254021632);
  float*  sc2   = (float*) (ws + 254025728);
  float*  sh2   = (float*) (ws + 254029824);
  float*  scd   = (float*) (ws + 254033920);
  float*  shd   = (float*) (ws + 254035968);

  dim3 b256(256);
  // conversions + weight transposes
  k_conv<<<dim3(16384), b256, 0, stream>>>(src, src_h, (long)NSRC*QDIM);
  k_conv<<<dim3(8192),  b256, 0, stream>>>(a1, a1_h, (long)MANC*QDIM);
  k_conv<<<dim3(1024),  b256, 0, stream>>>(a2, a2_h, (long)MANC*VDIM);
  k_transpose<<<dim3(DM/32, QDIM/32), b256, 0, stream>>>(Wq, WqT, QDIM, DM);
  k_transpose<<<dim3(DM/32, VDIM/32), b256, 0, stream>>>(Wv, WvT, VDIM, DM);
  k_transpose<<<dim3(FFD/32, DM/32),  b256, 0, stream>>>(W1, W1T, DM, FFD);
  k_transpose<<<dim3(DM/32, FFD/32),  b256, 0, stream>>>(W2, W2T, FFD, DM);
  k_transpose<<<dim3(VDIM/32, DM/32), b256, 0, stream>>>(Wd, WdT, DM, VDIM);
  // Q, K, V^T   (1D swizzled grids: nwg = (N/128)*(M/128))
  k_gemm<0><<<dim3(512),  b256, 0, stream>>>(src_h, WqT, NSRC, DM, QDIM, bq, nullptr, 1.f, nullptr, Qh, 7, 3);
  k_gemm<0><<<dim3(256),  b256, 0, stream>>>(a1_h, WqT, MANC, DM, QDIM, bq, nullptr, 1.f, nullptr, Kh, 7, 3);
  k_gemm<1><<<dim3(256),  b256, 0, stream>>>(a2_h, WvT, MANC, DM, VDIM, bv, nullptr, 1.f, nullptr, VTh, 7, 3);
  // scores = (Q K^T)/32 * label_graph ; softmax ; x = prob V
  k_gemm<2><<<dim3(2048), b256, 0, stream>>>(Qh, Kh, NSRC, MANC, DM, nullptr, lg, 0.03125f, scores, nullptr, 31, 5);
  k_softmax<<<dim3(NSRC), b256, 0, stream>>>(scores, prob);
  k_gemm<3><<<dim3(512),  b256, 0, stream>>>(prob, VTh, NSRC, DM, MANC, nullptr, nullptr, 1.f/512.f, x_att, nullptr, 7, 3);
  // BN1
  k_bn_partial<<<dim3(DM/256, 32), b256, 0, stream>>>(x_att, ps, pq, DM, NSRC/32);
  k_bn_final<<<dim3(DM/256), b256, 0, stream>>>(ps, pq, g1, be1, sc1, sh1, DM, 1.f/NSRC, 32);
  k_bn_apply<<<dim3(8192), b256, 0, stream>>>(x_att, sc1, sh1, xn, xnb, DM, (long)NSRC*DM);
  // FFN
  k_gemm<4><<<dim3(1024), b256, 0, stream>>>(xnb, W1T, NSRC, FFD, DM, b1, nullptr, 1.f, nullptr, hbuf, 15, 4);
  k_gemm<5><<<dim3(512),  b256, 0, stream>>>(hbuf, W2T, NSRC, DM, FFD, b2, xn, 1.f, x2, nullptr, 7, 3);
  // BN2
  k_bn_partial<<<dim3(DM/256, 32), b256, 0, stream>>>(x2, ps, pq, DM, NSRC/32);
  k_bn_final<<<dim3(DM/256), b256, 0, stream>>>(ps, pq, g2, be2, sc2, sh2, DM, 1.f/NSRC, 32);
  k_bn_apply<<<dim3(8192), b256, 0, stream>>>(x2, sc2, sh2, nullptr, x2nb, DM, (long)NSRC*DM);
  // decoder + BN + tanh
  k_gemm<6><<<dim3(256),  b256, 0, stream>>>(x2nb, WdT, NSRC, VDIM, DM, bd, nullptr, 1.f, y, nullptr, 3, 2);
  k_bn_partial<<<dim3(VDIM/256, 32), b256, 0, stream>>>(y, ps, pq, VDIM, NSRC/32);
  k_bn_final<<<dim3(2), b256, 0, stream>>>(ps, pq, gd, bed, scd, shd, VDIM, 1.f/NSRC, 32);
  k_bn_tanh<<<dim3(4096), b256, 0, stream>>>(y, scd, shd, (float*)d_out, VDIM, (long)NSRC*VDIM);
}

// Round 3
// 806.982 us; speedup vs baseline: 2.6079x; 1.0534x over previous
//
#include <hip/hip_runtime.h>

typedef __attribute__((ext_vector_type(4))) float f32x4;
typedef __attribute__((ext_vector_type(8))) _Float16 f16x8;

#define NSRC 8192
#define MANC 4096
#define QDIM 4096
#define VDIM 512
#define DM   1024
#define FFD  2048

__device__ __forceinline__ ushort f2h(float f){ _Float16 h=(_Float16)f; return __builtin_bit_cast(ushort,h); }
__device__ __forceinline__ float h2f(ushort u){ _Float16 h=__builtin_bit_cast(_Float16,u); return (float)h; }
__device__ __forceinline__ uint pk2(float a,float b){ return (uint)f2h(a) | ((uint)f2h(b)<<16); }

__device__ __forceinline__ void gload16(const ushort* g, ushort* l){
  __builtin_amdgcn_global_load_lds(
    (const __attribute__((address_space(1))) unsigned int*)g,
    (__attribute__((address_space(3))) unsigned int*)l, 16, 0, 0);
}

// ---------- merged weight transposes: W[K][N] f32 -> WT[N][K] f16 ----------
__device__ __forceinline__ void tr32(const float* __restrict__ W, ushort* __restrict__ WT,
                                     int K, int N, int bx, int by, int tid){
  __shared__ float tile[32][33];
  int n0 = bx*32, k0 = by*32;
  int tx = tid & 31, ty = tid >> 5;
  #pragma unroll
  for (int i=0;i<4;++i) tile[ty+i*8][tx] = W[(long)(k0+ty+i*8)*N + n0+tx];
  __syncthreads();
  #pragma unroll
  for (int i=0;i<4;++i){ int nn=ty+i*8; WT[(long)(n0+nn)*K + k0+tx] = f2h(tile[tx][nn]); }
}
__global__ __launch_bounds__(256) void k_prep(const float* __restrict__ Wq, const float* __restrict__ Wv,
    const float* __restrict__ W1, const float* __restrict__ W2, const float* __restrict__ Wd,
    ushort* __restrict__ WqT, ushort* __restrict__ WvT, ushort* __restrict__ W1T,
    ushort* __restrict__ W2T, ushort* __restrict__ WdT){
  int b = blockIdx.x, t = threadIdx.x;
  if (b < 4096)                 tr32(Wq, WqT, QDIM, DM,  b % 32,        b / 32,        t);
  else if (b < 4608)            tr32(Wv, WvT, VDIM, DM,  (b-4096)%32,   (b-4096)/32,   t);
  else if (b < 6656)            tr32(W1, W1T, DM,  FFD,  (b-4608)%64,   (b-4608)/64,   t);
  else if (b < 8704)            tr32(W2, W2T, FFD, DM,   (b-6656)%32,   (b-6656)/32,   t);
  else                          tr32(Wd, WdT, DM,  VDIM, (b-8704)%16,   (b-8704)/16,   t);
}

// ---------- generic f16 GEMM: C[M,N] = A[M,K] * Bt[N,K]^T ----------
// A32: A is f32 in global; reg-stage + convert + swizzled ds_write (fused conversion),
//      with next-tile register prefetch overlapped with MFMA.
// EPI: 0 f16 out +bias | 1 f16 out transposed +bias | 2 f16 out *alpha*extra(f32) |
//      3 f32 out *alpha | 4 f16 out tanh(+bias) | 5 f32 out +bias+extra(f16) | 6 f32 out +bias
template<int EPI, bool A32>
__global__ __launch_bounds__(256,2) void k_gemm(const void* __restrict__ Av, const ushort* __restrict__ Bt,
    int M, int N, int K, const float* __restrict__ bias, const void* __restrict__ extra,
    float alpha, float* __restrict__ Cf, ushort* __restrict__ Ch, int gxm1, int lg2gx)
{
  __shared__ ushort As[128*64];
  __shared__ ushort Bs[128*64];
  const int tid = threadIdx.x, lane = tid & 63, w = tid>>6;
  const int wm = (w>>1)*64, wn = (w&1)*64;
  int id = blockIdx.x;
  int nid = (id & 7)*((int)gridDim.x >> 3) + (id >> 3);
  const int m0 = (nid >> lg2gx)*128, n0 = (nid & gxm1)*128;
  const int lr = lane & 15, kg = lane >> 4;
  f32x4 acc[4][4] = {};
  const int nkt = K >> 6;
  const ushort* Ah = (const ushort*)Av + (A32 ? 0 : (long)m0*K);
  const float*  Af = (const float*)Av  + (A32 ? (long)m0*K : 0);
  const ushort* Bp = Bt + (long)n0*K;
  // staging map: 16B chunk c holds row c>>3, col-chunk (c&7)^(row&7)
  int rowj[4], colj[4];
  #pragma unroll
  for (int j=0;j<4;++j){
    int c = w*256 + j*64 + lane;
    rowj[j] = c>>3; colj[j] = (c&7) ^ (rowj[j]&7);
  }
  float4 pa[4][2];
  if (A32){
    #pragma unroll
    for (int j=0;j<4;++j){
      const float* s = Af + (long)rowj[j]*K + colj[j]*8;
      pa[j][0] = *(const float4*)s; pa[j][1] = *(const float4*)(s+4);
    }
  }
  for (int kt=0; kt<nkt; ++kt){
    __syncthreads();                       // prior compute done before overwrite
    long ko = (long)kt*64;
    if (A32){
      #pragma unroll
      for (int j=0;j<4;++j){
        uint4 o; o.x=pk2(pa[j][0].x,pa[j][0].y); o.y=pk2(pa[j][0].z,pa[j][0].w);
        o.z=pk2(pa[j][1].x,pa[j][1].y); o.w=pk2(pa[j][1].z,pa[j][1].w);
        *(uint4*)&As[(w*256 + j*64 + lane)*8] = o;
      }
    } else {
      #pragma unroll
      for (int j=0;j<4;++j)
        gload16(Ah + (long)rowj[j]*K + ko + colj[j]*8, As + (w*4+j)*512);
    }
    #pragma unroll
    for (int j=0;j<4;++j)
      gload16(Bp + (long)rowj[j]*K + ko + colj[j]*8, Bs + (w*4+j)*512);
    __syncthreads();                       // staging visible
    if (A32 && kt+1 < nkt){                // prefetch next A tile; waitcnt lands at next ds_write
      long ko2 = ko + 64;
      #pragma unroll
      for (int j=0;j<4;++j){
        const float* s = Af + (long)rowj[j]*K + ko2 + colj[j]*8;
        pa[j][0] = *(const float4*)s; pa[j][1] = *(const float4*)(s+4);
      }
    }
    #pragma unroll
    for (int ks=0; ks<2; ++ks){
      f16x8 af[4], bfr[4];
      #pragma unroll
      for (int mi=0;mi<4;++mi){
        int r = wm + mi*16 + lr, c = ks*4 + kg;
        af[mi] = *(const f16x8*)&As[r*64 + ((c ^ (r&7))*8)];
      }
      #pragma unroll
      for (int ni=0;ni<4;++ni){
        int r = wn + ni*16 + lr, c = ks*4 + kg;
        bfr[ni] = *(const f16x8*)&Bs[r*64 + ((c ^ (r&7))*8)];
      }
      #pragma unroll
      for (int mi=0;mi<4;++mi)
        #pragma unroll
        for (int ni=0;ni<4;++ni)
          acc[mi][ni] = __builtin_amdgcn_mfma_f32_16x16x32_f16(af[mi], bfr[ni], acc[mi][ni], 0,0,0);
    }
  }
  // ---- epilogue: transpose 16x64 slices through LDS -> coalesced stores ----
  __syncthreads();
  float* Lw = ((float*)As) + w*1024;       // per-wave 16x64 f32 slice
  #pragma unroll
  for (int mi=0;mi<4;++mi){
    #pragma unroll
    for (int ni=0;ni<4;++ni)
      #pragma unroll
      for (int r=0;r<4;++r)
        Lw[(kg*4+r)*64 + ni*16 + lr] = acc[mi][ni][r];
    __syncthreads();
    #pragma unroll
    for (int t=0;t<4;++t){
      int fi = t*64 + lane;
      int row16 = fi >> 4, c4 = fi & 15;
      float4 v4 = *(float4*)&Lw[row16*64 + c4*4];
      int row = m0 + wm + mi*16 + row16;
      int col = n0 + wn + c4*4;
      if (EPI==0){
        float4 b4 = *(const float4*)&bias[col];
        ushort4 o; o.x=f2h(v4.x+b4.x); o.y=f2h(v4.y+b4.y); o.z=f2h(v4.z+b4.z); o.w=f2h(v4.w+b4.w);
        *(ushort4*)&Ch[(long)row*N + col] = o;
      } else if (EPI==1){
        float4 b4 = *(const float4*)&bias[col];
        Ch[(long)(col+0)*M + row] = f2h(v4.x+b4.x);
        Ch[(long)(col+1)*M + row] = f2h(v4.y+b4.y);
        Ch[(long)(col+2)*M + row] = f2h(v4.z+b4.z);
        Ch[(long)(col+3)*M + row] = f2h(v4.w+b4.w);
      } else if (EPI==2){
        float4 e4 = *(const float4*)((const float*)extra + (long)row*N + col);
        ushort4 o; o.x=f2h(v4.x*alpha*e4.x); o.y=f2h(v4.y*alpha*e4.y);
        o.z=f2h(v4.z*alpha*e4.z); o.w=f2h(v4.w*alpha*e4.w);
        *(ushort4*)&Ch[(long)row*N + col] = o;
      } else if (EPI==3){
        float4 o; o.x=v4.x*alpha; o.y=v4.y*alpha; o.z=v4.z*alpha; o.w=v4.w*alpha;
        *(float4*)&Cf[(long)row*N + col] = o;
      } else if (EPI==4){
        float4 b4 = *(const float4*)&bias[col];
        ushort4 o; o.x=f2h(tanhf(v4.x+b4.x)); o.y=f2h(tanhf(v4.y+b4.y));
        o.z=f2h(tanhf(v4.z+b4.z)); o.w=f2h(tanhf(v4.w+b4.w));
        *(ushort4*)&Ch[(long)row*N + col] = o;
      } else if (EPI==5){
        float4 b4 = *(const float4*)&bias[col];
        ushort4 e4 = *(const ushort4*)((const ushort*)extra + (long)row*N + col);
        float4 o; o.x=v4.x+b4.x+h2f(e4.x); o.y=v4.y+b4.y+h2f(e4.y);
        o.z=v4.z+b4.z+h2f(e4.z); o.w=v4.w+b4.w+h2f(e4.w);
        *(float4*)&Cf[(long)row*N + col] = o;
      } else {
        float4 b4 = *(const float4*)&bias[col];
        float4 o; o.x=v4.x+b4.x; o.y=v4.y+b4.y; o.z=v4.z+b4.z; o.w=v4.w+b4.w;
        *(float4*)&Cf[(long)row*N + col] = o;
      }
    }
    __syncthreads();
  }
}

// ---------- row softmax over 4096 f16 cols, writes prob*512 as f16 ----------
__global__ __launch_bounds__(256) void k_softmax(const ushort* __restrict__ S, ushort* __restrict__ P){
  const long base = (long)blockIdx.x * 4096;
  const int t = threadIdx.x;
  uint u[8];
  *(uint4*)&u[0] = *(const uint4*)(S + base + t*16);
  *(uint4*)&u[4] = *(const uint4*)(S + base + t*16 + 8);
  float v[16];
  #pragma unroll
  for (int i=0;i<8;++i){ v[2*i]=h2f((ushort)(u[i]&0xffff)); v[2*i+1]=h2f((ushort)(u[i]>>16)); }
  float mx = -3.4e38f;
  #pragma unroll
  for (int i=0;i<16;++i) mx = fmaxf(mx, v[i]);
  #pragma unroll
  for (int off=1; off<64; off<<=1) mx = fmaxf(mx, __shfl_xor(mx, off));
  __shared__ float red[8];
  int wv = t>>6;
  if ((t&63)==0) red[wv]=mx;
  __syncthreads();
  mx = fmaxf(fmaxf(red[0],red[1]), fmaxf(red[2],red[3]));
  float e[16]; float sum=0.f;
  #pragma unroll
  for (int i=0;i<16;++i){ e[i]=__expf(v[i]-mx); sum+=e[i]; }
  #pragma unroll
  for (int off=1; off<64; off<<=1) sum += __shfl_xor(sum, off);
  if ((t&63)==0) red[4+wv]=sum;
  __syncthreads();
  sum = red[4]+red[5]+red[6]+red[7];
  float s = 512.f/sum;   // x512 keeps tiny probs in f16-normal range; folded out in PV
  uint o[8];
  #pragma unroll
  for (int i=0;i<8;++i) o[i]=pk2(e[2*i]*s, e[2*i+1]*s);
  *(uint4*)(P + base + t*16)     = *(uint4*)&o[0];
  *(uint4*)(P + base + t*16 + 8) = *(uint4*)&o[4];
}

// ---------- batchnorm: partial sums / finalize / apply ----------
__global__ __launch_bounds__(256) void k_bn_partial(const float* __restrict__ X, float* __restrict__ ps, float* __restrict__ pq, int F, int rowsPer){
  int col = blockIdx.x*256 + threadIdx.x;
  long r0 = (long)blockIdx.y * rowsPer;
  float s=0.f,q=0.f;
  for (int r=0;r<rowsPer;++r){ float x = X[(r0+r)*F + col]; s+=x; q+=x*x; }
  ps[(long)blockIdx.y*F + col]=s; pq[(long)blockIdx.y*F + col]=q;
}
__global__ __launch_bounds__(256) void k_bn_final(const float* __restrict__ ps, const float* __restrict__ pq,
    const float* __restrict__ gamma, const float* __restrict__ beta,
    float* __restrict__ scale, float* __restrict__ shift, int F, float invN, int nch){
  int c = blockIdx.x*256 + threadIdx.x;
  if (c>=F) return;
  float s=0.f,q=0.f;
  for (int i=0;i<nch;++i){ s+=ps[i*F+c]; q+=pq[i*F+c]; }
  float mu = s*invN, var = q*invN - mu*mu;
  float sc = gamma[c]*rsqrtf(var+1e-5f);
  scale[c]=sc; shift[c]=beta[c]-mu*sc;
}
__global__ __launch_bounds__(256) void k_bn_apply(const float* __restrict__ X, const float* __restrict__ scale, const float* __restrict__ shift,
    ushort* __restrict__ Xh, int F, long n){
  long i = ((long)blockIdx.x*256 + threadIdx.x)*4;
  if (i>=n) return;
  int c = (int)(i & (long)(F-1));
  float4 x = *(const float4*)(X+i);
  ushort4 o; o.x=f2h(x.x*scale[c]+shift[c]); o.y=f2h(x.y*scale[c+1]+shift[c+1]);
  o.z=f2h(x.z*scale[c+2]+shift[c+2]); o.w=f2h(x.w*scale[c+3]+shift[c+3]);
  *(ushort4*)(Xh+i)=o;
}
__global__ __launch_bounds__(256) void k_bn_tanh(const float* __restrict__ X, const float* __restrict__ scale, const float* __restrict__ shift,
    float* __restrict__ O, int F, long n){
  long i = ((long)blockIdx.x*256 + threadIdx.x)*4;
  if (i>=n) return;
  int c = (int)(i & (long)(F-1));
  float4 x = *(const float4*)(X+i);
  float4 y; y.x=tanhf(x.x*scale[c]+shift[c]); y.y=tanhf(x.y*scale[c+1]+shift[c+1]);
  y.z=tanhf(x.z*scale[c+2]+shift[c+2]); y.w=tanhf(x.w*scale[c+3]+shift[c+3]);
  *(float4*)(O+i)=y;
}

extern "C" void kernel_launch(void* const* d_in, const int* in_sizes, int n_in,
                              void* d_out, int out_size, void* d_ws, size_t ws_size,
                              hipStream_t stream){
  const float* src = (const float*)d_in[0];
  const float* a1  = (const float*)d_in[1];
  const float* a2  = (const float*)d_in[2];
  const float* lg  = (const float*)d_in[3];
  const float* Wq  = (const float*)d_in[4];
  const float* bq  = (const float*)d_in[5];
  const float* Wv  = (const float*)d_in[6];
  const float* bv  = (const float*)d_in[7];
  const float* W1  = (const float*)d_in[8];
  const float* b1  = (const float*)d_in[9];
  const float* W2  = (const float*)d_in[10];
  const float* b2  = (const float*)d_in[11];
  const float* g1  = (const float*)d_in[12];
  const float* be1 = (const float*)d_in[13];
  const float* g2  = (const float*)d_in[14];
  const float* be2 = (const float*)d_in[15];
  const float* Wd  = (const float*)d_in[16];
  const float* bd  = (const float*)d_in[17];
  const float* gd  = (const float*)d_in[18];
  const float* bed = (const float*)d_in[19];
  char* ws = (char*)d_ws;
  // region R0 (lifetime-aliased): scores f16 [0,64MiB) -> x_att f32 [0,32MiB)
  ushort* scores= (ushort*)(ws + 0);
  float*  x_att = (float*) (ws + 0);
  ushort* xnb   = (ushort*)(ws + 67108864);   // 64MiB, 16MiB
  ushort* hbuf  = (ushort*)(ws + 83886080);   // 80MiB, 32MiB
  // region R1: prob f16 [128,192MiB) -> x2 f32 [128,160), x2nb [160,176), y [176,192)
  ushort* prob  = (ushort*)(ws + 134217728);
  float*  x2    = (float*) (ws + 134217728);
  ushort* x2nb  = (ushort*)(ws + 167772160);
  float*  y     = (float*) (ws + 184549376);
  // persistent (>=192MiB)
  ushort* Qh    = (ushort*)(ws + 201326592);
  ushort* Kh    = (ushort*)(ws + 218103808);
  ushort* VTh   = (ushort*)(ws + 226492416);
  ushort* WqT   = (ushort*)(ws + 234881024);
  ushort* WvT   = (ushort*)(ws + 243269632);
  ushort* W1T   = (ushort*)(ws + 244318208);
  ushort* W2T   = (ushort*)(ws + 248512512);
  ushort* WdT   = (ushort*)(ws + 252706816);
  float*  ps    = (float*) (ws + 253755392);
  float*  pq    = (float*) (ws + 253886464);
  float*  sc1   = (float*) (ws + 254017536);
  float*  sh1   = (float*) (ws + 254021632);
  float*  sc2   = (float*) (ws + 254025728);
  float*  sh2   = (float*) (ws + 254029824);
  float*  scd   = (float*) (ws + 254033920);
  float*  shd   = (float*) (ws + 254035968);

  dim3 b256(256);
  // weight transposes (one dispatch)
  k_prep<<<dim3(9216), b256, 0, stream>>>(Wq, Wv, W1, W2, Wd, WqT, WvT, W1T, W2T, WdT);
  // Q, K, V^T with fused f32->f16 A conversion
  k_gemm<0,true><<<dim3(512),  b256, 0, stream>>>(src, WqT, NSRC, DM, QDIM, bq, nullptr, 1.f, nullptr, Qh, 7, 3);
  k_gemm<0,true><<<dim3(256),  b256, 0, stream>>>(a1, WqT, MANC, DM, QDIM, bq, nullptr, 1.f, nullptr, Kh, 7, 3);
  k_gemm<1,true><<<dim3(256),  b256, 0, stream>>>(a2, WvT, MANC, DM, VDIM, bv, nullptr, 1.f, nullptr, VTh, 7, 3);
  // scores(f16) = (Q K^T)/32 * label_graph ; softmax(f16) ; x = prob V
  k_gemm<2,false><<<dim3(2048), b256, 0, stream>>>(Qh, Kh, NSRC, MANC, DM, nullptr, lg, 0.03125f, nullptr, scores, 31, 5);
  k_softmax<<<dim3(NSRC), b256, 0, stream>>>(scores, prob);
  k_gemm<3,false><<<dim3(512),  b256, 0, stream>>>(prob, VTh, NSRC, DM, MANC, nullptr, nullptr, 1.f/512.f, x_att, nullptr, 7, 3);
  // BN1
  k_bn_partial<<<dim3(DM/256, 32), b256, 0, stream>>>(x_att, ps, pq, DM, NSRC/32);
  k_bn_final<<<dim3(DM/256), b256, 0, stream>>>(ps, pq, g1, be1, sc1, sh1, DM, 1.f/NSRC, 32);
  k_bn_apply<<<dim3(8192), b256, 0, stream>>>(x_att, sc1, sh1, xnb, DM, (long)NSRC*DM);
  // FFN (residual read as f16 xnb in EPI5)
  k_gemm<4,false><<<dim3(1024), b256, 0, stream>>>(xnb, W1T, NSRC, FFD, DM, b1, nullptr, 1.f, nullptr, hbuf, 15, 4);
  k_gemm<5,false><<<dim3(512),  b256, 0, stream>>>(hbuf, W2T, NSRC, DM, FFD, b2, xnb, 1.f, x2, nullptr, 7, 3);
  // BN2
  k_bn_partial<<<dim3(DM/256, 32), b256, 0, stream>>>(x2, ps, pq, DM, NSRC/32);
  k_bn_final<<<dim3(DM/256), b256, 0, stream>>>(ps, pq, g2, be2, sc2, sh2, DM, 1.f/NSRC, 32);
  k_bn_apply<<<dim3(8192), b256, 0, stream>>>(x2, sc2, sh2, x2nb, DM, (long)NSRC*DM);
  // decoder + BN + tanh
  k_gemm<6,false><<<dim3(256),  b256, 0, stream>>>(x2nb, WdT, NSRC, VDIM, DM, bd, nullptr, 1.f, y, nullptr, 3, 2);
  k_bn_partial<<<dim3(VDIM/256, 32), b256, 0, stream>>>(y, ps, pq, VDIM, NSRC/32);
  k_bn_final<<<dim3(2), b256, 0, stream>>>(ps, pq, gd, bed, scd, shd, VDIM, 1.f/NSRC, 32);
  k_bn_tanh<<<dim3(4096), b256, 0, stream>>>(y, scd, shd, (float*)d_out, VDIM, (long)NSRC*VDIM);
}

// Round 4
// 782.010 us; speedup vs baseline: 2.6911x; 1.0319x over previous
//
#include <hip/hip_runtime.h>

typedef __attribute__((ext_vector_type(4))) float f32x4;
typedef __attribute__((ext_vector_type(8))) _Float16 f16x8;

#define NSRC 8192
#define MANC 4096
#define QDIM 4096
#define VDIM 512
#define DM   1024
#define FFD  2048

__device__ __forceinline__ ushort f2h(float f){ _Float16 h=(_Float16)f; return __builtin_bit_cast(ushort,h); }
__device__ __forceinline__ float h2f(ushort u){ _Float16 h=__builtin_bit_cast(_Float16,u); return (float)h; }
__device__ __forceinline__ uint pk2(float a,float b){ return (uint)f2h(a) | ((uint)f2h(b)<<16); }

__device__ __forceinline__ void gload16(const ushort* g, ushort* l){
  __builtin_amdgcn_global_load_lds(
    (const __attribute__((address_space(1))) unsigned int*)g,
    (__attribute__((address_space(3))) unsigned int*)l, 16, 0, 0);
}

// ---------- f32 -> f16 convert (src only) ----------
__global__ __launch_bounds__(256) void k_conv(const float* __restrict__ in, ushort* __restrict__ out, long n){
  long i = ((long)blockIdx.x*256 + threadIdx.x)*8;
  if (i >= n) return;
  float4 a = *(const float4*)(in+i);
  float4 b = *(const float4*)(in+i+4);
  uint4 o; o.x=pk2(a.x,a.y); o.y=pk2(a.z,a.w); o.z=pk2(b.x,b.y); o.w=pk2(b.z,b.w);
  *(uint4*)(out+i) = o;
}

// ---------- merged weight transposes: W[K][N] f32 -> WT[N][K] f16 ----------
__device__ __forceinline__ void tr32(const float* __restrict__ W, ushort* __restrict__ WT,
                                     int K, int N, int bx, int by, int tid){
  __shared__ float tile[32][33];
  int n0 = bx*32, k0 = by*32;
  int tx = tid & 31, ty = tid >> 5;
  #pragma unroll
  for (int i=0;i<4;++i) tile[ty+i*8][tx] = W[(long)(k0+ty+i*8)*N + n0+tx];
  __syncthreads();
  #pragma unroll
  for (int i=0;i<4;++i){ int nn=ty+i*8; WT[(long)(n0+nn)*K + k0+tx] = f2h(tile[tx][nn]); }
}
__global__ __launch_bounds__(256) void k_prep(const float* __restrict__ Wq, const float* __restrict__ Wv,
    const float* __restrict__ W1, const float* __restrict__ W2, const float* __restrict__ Wd,
    ushort* __restrict__ WqT, ushort* __restrict__ WvT, ushort* __restrict__ W1T,
    ushort* __restrict__ W2T, ushort* __restrict__ WdT){
  int b = blockIdx.x, t = threadIdx.x;
  if (b < 4096)                 tr32(Wq, WqT, QDIM, DM,  b % 32,        b / 32,        t);
  else if (b < 4608)            tr32(Wv, WvT, VDIM, DM,  (b-4096)%32,   (b-4096)/32,   t);
  else if (b < 6656)            tr32(W1, W1T, DM,  FFD,  (b-4608)%64,   (b-4608)/64,   t);
  else if (b < 8704)            tr32(W2, W2T, FFD, DM,   (b-6656)%32,   (b-6656)/32,   t);
  else                          tr32(Wd, WdT, DM,  VDIM, (b-8704)%16,   (b-8704)/16,   t);
}

// ================= deep-pipelined 256x128 GEMM (counted vmcnt) =================
// C[M,N] = A[M,K](f16) * Bt[N,K]^T(f16). 512 thr = 8 waves (4M x 2N), 64x64/wave.
// LDS ring: 2 x (A 32KB + B 16KB) = 96KB. Per K-tile: read frags -> ks0 MFMA ->
// lgkm(0)+barrier -> stage tile t+2 into freed buf -> ks1 MFMA -> vmcnt(6) -> barrier.
// EPI: 0 f16+bias | 2 f16 *alpha*extra(f32) | 3 f32 *alpha | 4 f16 tanh(+bias) | 5 f32 +bias+extra(f16)
template<int EPI>
__global__ __launch_bounds__(512,1) void k_gemm2(const ushort* __restrict__ A, const ushort* __restrict__ Bt,
    int M, int N, int K, const float* __restrict__ bias, const void* __restrict__ extra,
    float alpha, float* __restrict__ Cf, ushort* __restrict__ Ch, int gxm1, int lg2gx)
{
  extern __shared__ ushort lds[];
  const int tid = threadIdx.x, lane = tid & 63, w = tid >> 6;
  const int wm = (w >> 1) * 64, wn = (w & 1) * 64;
  int id = blockIdx.x;
  int nid = (id & 7) * ((int)gridDim.x >> 3) + (id >> 3);
  const int m0 = (nid >> lg2gx) * 256, n0 = (nid & gxm1) * 128;
  const int lr = lane & 15, kg = lane >> 4;
  f32x4 acc[4][4] = {};
  const int nkt = K >> 6;
  const ushort* Ap = A + (long)m0 * K;
  const ushort* Bp = Bt + (long)n0 * K;
  // staging map: 16B chunk c = j*512 + w*64 + lane; row=c>>3, col-chunk=(c&7)^(row&7)
  int ar[4], ac[4];
  #pragma unroll
  for (int j = 0; j < 4; ++j){
    int c = j*512 + w*64 + lane;
    ar[j] = c >> 3; ac[j] = (c & 7) ^ (ar[j] & 7);
  }
  ushort* Abuf0 = lds;            // 16384 shorts
  ushort* Bbuf0 = lds + 16384;    //  8192
  ushort* Abuf1 = lds + 24576;
  ushort* Bbuf1 = lds + 40960;    // total 49152 shorts = 96KB
  // prologue: stage tiles 0 and 1
  #pragma unroll
  for (int j = 0; j < 4; ++j) gload16(Ap + (long)ar[j]*K + ac[j]*8, Abuf0 + (j*512 + w*64)*8);
  #pragma unroll
  for (int j = 0; j < 2; ++j) gload16(Bp + (long)ar[j]*K + ac[j]*8, Bbuf0 + (j*512 + w*64)*8);
  #pragma unroll
  for (int j = 0; j < 4; ++j) gload16(Ap + (long)ar[j]*K + 64 + ac[j]*8, Abuf1 + (j*512 + w*64)*8);
  #pragma unroll
  for (int j = 0; j < 2; ++j) gload16(Bp + (long)ar[j]*K + 64 + ac[j]*8, Bbuf1 + (j*512 + w*64)*8);
  asm volatile("s_waitcnt vmcnt(6)" ::: "memory");   // tile0 landed (tile1's 6 in flight)
  __builtin_amdgcn_sched_barrier(0);
  __builtin_amdgcn_s_barrier();
  __builtin_amdgcn_sched_barrier(0);
  int cur = 0;
  for (int t = 0; t < nkt; ++t){
    const ushort* Ar = cur ? Abuf1 : Abuf0;
    const ushort* Br = cur ? Bbuf1 : Bbuf0;
    f16x8 a0[4], b0[4], a1[4], b1[4];
    #pragma unroll
    for (int mi = 0; mi < 4; ++mi){
      int r = wm + mi*16 + lr;
      a0[mi] = *(const f16x8*)&Ar[r*64 + ((kg     ^ (r&7))*8)];
      a1[mi] = *(const f16x8*)&Ar[r*64 + (((4+kg) ^ (r&7))*8)];
    }
    #pragma unroll
    for (int ni = 0; ni < 4; ++ni){
      int r = wn + ni*16 + lr;
      b0[ni] = *(const f16x8*)&Br[r*64 + ((kg     ^ (r&7))*8)];
      b1[ni] = *(const f16x8*)&Br[r*64 + (((4+kg) ^ (r&7))*8)];
    }
    __builtin_amdgcn_s_setprio(1);
    #pragma unroll
    for (int mi = 0; mi < 4; ++mi)
      #pragma unroll
      for (int ni = 0; ni < 4; ++ni)
        acc[mi][ni] = __builtin_amdgcn_mfma_f32_16x16x32_f16(a0[mi], b0[ni], acc[mi][ni], 0,0,0);
    __builtin_amdgcn_s_setprio(0);
    asm volatile("s_waitcnt lgkmcnt(0)" ::: "memory");  // my frag reads retired
    __builtin_amdgcn_sched_barrier(0);
    __builtin_amdgcn_s_barrier();                       // all waves done reading buf[cur]
    __builtin_amdgcn_sched_barrier(0);
    if (t + 2 < nkt){                                   // stage tile t+2 into freed buf[cur]
      long ko = (long)(t+2)*64;
      ushort* Ad = cur ? Abuf1 : Abuf0;
      ushort* Bd = cur ? Bbuf1 : Bbuf0;
      #pragma unroll
      for (int j = 0; j < 4; ++j) gload16(Ap + (long)ar[j]*K + ko + ac[j]*8, Ad + (j*512 + w*64)*8);
      #pragma unroll
      for (int j = 0; j < 2; ++j) gload16(Bp + (long)ar[j]*K + ko + ac[j]*8, Bd + (j*512 + w*64)*8);
    }
    __builtin_amdgcn_s_setprio(1);                      // ks1 MFMA overlaps staged loads
    #pragma unroll
    for (int mi = 0; mi < 4; ++mi)
      #pragma unroll
      for (int ni = 0; ni < 4; ++ni)
        acc[mi][ni] = __builtin_amdgcn_mfma_f32_16x16x32_f16(a1[mi], b1[ni], acc[mi][ni], 0,0,0);
    __builtin_amdgcn_s_setprio(0);
    if (t + 2 < nkt)      { asm volatile("s_waitcnt vmcnt(6)" ::: "memory"); } // tile t+1 landed
    else if (t + 1 < nkt) { asm volatile("s_waitcnt vmcnt(0)" ::: "memory"); }
    __builtin_amdgcn_sched_barrier(0);
    __builtin_amdgcn_s_barrier();
    __builtin_amdgcn_sched_barrier(0);
    cur ^= 1;
  }
  // ---- epilogue: per-wave 64x64 via 4KB LDS slice -> coalesced stores ----
  __syncthreads();
  float* Lw = ((float*)lds) + w*1024;
  #pragma unroll
  for (int mi = 0; mi < 4; ++mi){
    #pragma unroll
    for (int ni = 0; ni < 4; ++ni)
      #pragma unroll
      for (int r = 0; r < 4; ++r)
        Lw[(kg*4+r)*64 + ni*16 + lr] = acc[mi][ni][r];
    __syncthreads();
    #pragma unroll
    for (int tt = 0; tt < 4; ++tt){
      int fi = tt*64 + lane;
      int row16 = fi >> 4, c4 = fi & 15;
      float4 v4 = *(float4*)&Lw[row16*64 + c4*4];
      int row = m0 + wm + mi*16 + row16;
      int col = n0 + wn + c4*4;
      if (EPI==0){
        float4 b4 = *(const float4*)&bias[col];
        ushort4 o; o.x=f2h(v4.x+b4.x); o.y=f2h(v4.y+b4.y); o.z=f2h(v4.z+b4.z); o.w=f2h(v4.w+b4.w);
        *(ushort4*)&Ch[(long)row*N + col] = o;
      } else if (EPI==2){
        float4 e4 = *(const float4*)((const float*)extra + (long)row*N + col);
        ushort4 o; o.x=f2h(v4.x*alpha*e4.x); o.y=f2h(v4.y*alpha*e4.y);
        o.z=f2h(v4.z*alpha*e4.z); o.w=f2h(v4.w*alpha*e4.w);
        *(ushort4*)&Ch[(long)row*N + col] = o;
      } else if (EPI==3){
        float4 o; o.x=v4.x*alpha; o.y=v4.y*alpha; o.z=v4.z*alpha; o.w=v4.w*alpha;
        *(float4*)&Cf[(long)row*N + col] = o;
      } else if (EPI==4){
        float4 b4 = *(const float4*)&bias[col];
        ushort4 o; o.x=f2h(tanhf(v4.x+b4.x)); o.y=f2h(tanhf(v4.y+b4.y));
        o.z=f2h(tanhf(v4.z+b4.z)); o.w=f2h(tanhf(v4.w+b4.w));
        *(ushort4*)&Ch[(long)row*N + col] = o;
      } else if (EPI==5){
        float4 b4 = *(const float4*)&bias[col];
        ushort4 e4 = *(const ushort4*)((const ushort*)extra + (long)row*N + col);
        float4 o; o.x=v4.x+b4.x+h2f(e4.x); o.y=v4.y+b4.y+h2f(e4.y);
        o.z=v4.z+b4.z+h2f(e4.z); o.w=v4.w+b4.w+h2f(e4.w);
        *(float4*)&Cf[(long)row*N + col] = o;
      }
    }
    __syncthreads();
  }
}

// ---------- legacy 128x128 GEMM (for K, V^T, decoder) ----------
// EPI: 0 f16 out +bias | 1 f16 out transposed +bias | 6 f32 out +bias
template<int EPI, bool A32>
__global__ __launch_bounds__(256,2) void k_gemm(const void* __restrict__ Av, const ushort* __restrict__ Bt,
    int M, int N, int K, const float* __restrict__ bias,
    float alpha, float* __restrict__ Cf, ushort* __restrict__ Ch, int gxm1, int lg2gx)
{
  __shared__ ushort As[128*64];
  __shared__ ushort Bs[128*64];
  const int tid = threadIdx.x, lane = tid & 63, w = tid>>6;
  const int wm = (w>>1)*64, wn = (w&1)*64;
  int id = blockIdx.x;
  int nid = (id & 7)*((int)gridDim.x >> 3) + (id >> 3);
  const int m0 = (nid >> lg2gx)*128, n0 = (nid & gxm1)*128;
  const int lr = lane & 15, kg = lane >> 4;
  f32x4 acc[4][4] = {};
  const int nkt = K >> 6;
  const ushort* Ah = (const ushort*)Av + (A32 ? 0 : (long)m0*K);
  const float*  Af = (const float*)Av  + (A32 ? (long)m0*K : 0);
  const ushort* Bp = Bt + (long)n0*K;
  int rowj[4], colj[4];
  #pragma unroll
  for (int j=0;j<4;++j){
    int c = w*256 + j*64 + lane;
    rowj[j] = c>>3; colj[j] = (c&7) ^ (rowj[j]&7);
  }
  float4 pa[4][2];
  if (A32){
    #pragma unroll
    for (int j=0;j<4;++j){
      const float* s = Af + (long)rowj[j]*K + colj[j]*8;
      pa[j][0] = *(const float4*)s; pa[j][1] = *(const float4*)(s+4);
    }
  }
  for (int kt=0; kt<nkt; ++kt){
    __syncthreads();
    long ko = (long)kt*64;
    if (A32){
      #pragma unroll
      for (int j=0;j<4;++j){
        uint4 o; o.x=pk2(pa[j][0].x,pa[j][0].y); o.y=pk2(pa[j][0].z,pa[j][0].w);
        o.z=pk2(pa[j][1].x,pa[j][1].y); o.w=pk2(pa[j][1].z,pa[j][1].w);
        *(uint4*)&As[(w*256 + j*64 + lane)*8] = o;
      }
    } else {
      #pragma unroll
      for (int j=0;j<4;++j)
        gload16(Ah + (long)rowj[j]*K + ko + colj[j]*8, As + (w*4+j)*512);
    }
    #pragma unroll
    for (int j=0;j<4;++j)
      gload16(Bp + (long)rowj[j]*K + ko + colj[j]*8, Bs + (w*4+j)*512);
    __syncthreads();
    if (A32 && kt+1 < nkt){
      long ko2 = ko + 64;
      #pragma unroll
      for (int j=0;j<4;++j){
        const float* s = Af + (long)rowj[j]*K + ko2 + colj[j]*8;
        pa[j][0] = *(const float4*)s; pa[j][1] = *(const float4*)(s+4);
      }
    }
    #pragma unroll
    for (int ks=0; ks<2; ++ks){
      f16x8 af[4], bfr[4];
      #pragma unroll
      for (int mi=0;mi<4;++mi){
        int r = wm + mi*16 + lr, c = ks*4 + kg;
        af[mi] = *(const f16x8*)&As[r*64 + ((c ^ (r&7))*8)];
      }
      #pragma unroll
      for (int ni=0;ni<4;++ni){
        int r = wn + ni*16 + lr, c = ks*4 + kg;
        bfr[ni] = *(const f16x8*)&Bs[r*64 + ((c ^ (r&7))*8)];
      }
      #pragma unroll
      for (int mi=0;mi<4;++mi)
        #pragma unroll
        for (int ni=0;ni<4;++ni)
          acc[mi][ni] = __builtin_amdgcn_mfma_f32_16x16x32_f16(af[mi], bfr[ni], acc[mi][ni], 0,0,0);
    }
  }
  __syncthreads();
  float* Lw = ((float*)As) + w*1024;
  #pragma unroll
  for (int mi=0;mi<4;++mi){
    #pragma unroll
    for (int ni=0;ni<4;++ni)
      #pragma unroll
      for (int r=0;r<4;++r)
        Lw[(kg*4+r)*64 + ni*16 + lr] = acc[mi][ni][r];
    __syncthreads();
    #pragma unroll
    for (int t=0;t<4;++t){
      int fi = t*64 + lane;
      int row16 = fi >> 4, c4 = fi & 15;
      float4 v4 = *(float4*)&Lw[row16*64 + c4*4];
      int row = m0 + wm + mi*16 + row16;
      int col = n0 + wn + c4*4;
      if (EPI==0){
        float4 b4 = *(const float4*)&bias[col];
        ushort4 o; o.x=f2h(v4.x+b4.x); o.y=f2h(v4.y+b4.y); o.z=f2h(v4.z+b4.z); o.w=f2h(v4.w+b4.w);
        *(ushort4*)&Ch[(long)row*N + col] = o;
      } else if (EPI==1){
        float4 b4 = *(const float4*)&bias[col];
        Ch[(long)(col+0)*M + row] = f2h(v4.x+b4.x);
        Ch[(long)(col+1)*M + row] = f2h(v4.y+b4.y);
        Ch[(long)(col+2)*M + row] = f2h(v4.z+b4.z);
        Ch[(long)(col+3)*M + row] = f2h(v4.w+b4.w);
      } else {
        float4 b4 = *(const float4*)&bias[col];
        float4 o; o.x=v4.x+b4.x; o.y=v4.y+b4.y; o.z=v4.z+b4.z; o.w=v4.w+b4.w;
        *(float4*)&Cf[(long)row*N + col] = o;
      }
    }
    __syncthreads();
  }
}

// ---------- row softmax over 4096 f16 cols, writes prob*512 as f16 ----------
__global__ __launch_bounds__(256) void k_softmax(const ushort* __restrict__ S, ushort* __restrict__ P){
  const long base = (long)blockIdx.x * 4096;
  const int t = threadIdx.x;
  uint u[8];
  *(uint4*)&u[0] = *(const uint4*)(S + base + t*16);
  *(uint4*)&u[4] = *(const uint4*)(S + base + t*16 + 8);
  float v[16];
  #pragma unroll
  for (int i=0;i<8;++i){ v[2*i]=h2f((ushort)(u[i]&0xffff)); v[2*i+1]=h2f((ushort)(u[i]>>16)); }
  float mx = -3.4e38f;
  #pragma unroll
  for (int i=0;i<16;++i) mx = fmaxf(mx, v[i]);
  #pragma unroll
  for (int off=1; off<64; off<<=1) mx = fmaxf(mx, __shfl_xor(mx, off));
  __shared__ float red[8];
  int wv = t>>6;
  if ((t&63)==0) red[wv]=mx;
  __syncthreads();
  mx = fmaxf(fmaxf(red[0],red[1]), fmaxf(red[2],red[3]));
  float e[16]; float sum=0.f;
  #pragma unroll
  for (int i=0;i<16;++i){ e[i]=__expf(v[i]-mx); sum+=e[i]; }
  #pragma unroll
  for (int off=1; off<64; off<<=1) sum += __shfl_xor(sum, off);
  if ((t&63)==0) red[4+wv]=sum;
  __syncthreads();
  sum = red[4]+red[5]+red[6]+red[7];
  float s = 512.f/sum;
  uint o[8];
  #pragma unroll
  for (int i=0;i<8;++i) o[i]=pk2(e[2*i]*s, e[2*i+1]*s);
  *(uint4*)(P + base + t*16)     = *(uint4*)&o[0];
  *(uint4*)(P + base + t*16 + 8) = *(uint4*)&o[4];
}

// ---------- batchnorm: partial sums / finalize / apply ----------
__global__ __launch_bounds__(256) void k_bn_partial(const float* __restrict__ X, float* __restrict__ ps, float* __restrict__ pq, int F, int rowsPer){
  int col = blockIdx.x*256 + threadIdx.x;
  long r0 = (long)blockIdx.y * rowsPer;
  float s=0.f,q=0.f;
  for (int r=0;r<rowsPer;++r){ float x = X[(r0+r)*F + col]; s+=x; q+=x*x; }
  ps[(long)blockIdx.y*F + col]=s; pq[(long)blockIdx.y*F + col]=q;
}
__global__ __launch_bounds__(256) void k_bn_final(const float* __restrict__ ps, const float* __restrict__ pq,
    const float* __restrict__ gamma, const float* __restrict__ beta,
    float* __restrict__ scale, float* __restrict__ shift, int F, float invN, int nch){
  int c = blockIdx.x*256 + threadIdx.x;
  if (c>=F) return;
  float s=0.f,q=0.f;
  for (int i=0;i<nch;++i){ s+=ps[i*F+c]; q+=pq[i*F+c]; }
  float mu = s*invN, var = q*invN - mu*mu;
  float sc = gamma[c]*rsqrtf(var+1e-5f);
  scale[c]=sc; shift[c]=beta[c]-mu*sc;
}
__global__ __launch_bounds__(256) void k_bn_apply(const float* __restrict__ X, const float* __restrict__ scale, const float* __restrict__ shift,
    ushort* __restrict__ Xh, int F, long n){
  long i = ((long)blockIdx.x*256 + threadIdx.x)*4;
  if (i>=n) return;
  int c = (int)(i & (long)(F-1));
  float4 x = *(const float4*)(X+i);
  ushort4 o; o.x=f2h(x.x*scale[c]+shift[c]); o.y=f2h(x.y*scale[c+1]+shift[c+1]);
  o.z=f2h(x.z*scale[c+2]+shift[c+2]); o.w=f2h(x.w*scale[c+3]+shift[c+3]);
  *(ushort4*)(Xh+i)=o;
}
__global__ __launch_bounds__(256) void k_bn_tanh(const float* __restrict__ X, const float* __restrict__ scale, const float* __restrict__ shift,
    float* __restrict__ O, int F, long n){
  long i = ((long)blockIdx.x*256 + threadIdx.x)*4;
  if (i>=n) return;
  int c = (int)(i & (long)(F-1));
  float4 x = *(const float4*)(X+i);
  float4 y; y.x=tanhf(x.x*scale[c]+shift[c]); y.y=tanhf(x.y*scale[c+1]+shift[c+1]);
  y.z=tanhf(x.z*scale[c+2]+shift[c+2]); y.w=tanhf(x.w*scale[c+3]+shift[c+3]);
  *(float4*)(O+i)=y;
}

extern "C" void kernel_launch(void* const* d_in, const int* in_sizes, int n_in,
                              void* d_out, int out_size, void* d_ws, size_t ws_size,
                              hipStream_t stream){
  const float* src = (const float*)d_in[0];
  const float* a1  = (const float*)d_in[1];
  const float* a2  = (const float*)d_in[2];
  const float* lg  = (const float*)d_in[3];
  const float* Wq  = (const float*)d_in[4];
  const float* bq  = (const float*)d_in[5];
  const float* Wv  = (const float*)d_in[6];
  const float* bv  = (const float*)d_in[7];
  const float* W1  = (const float*)d_in[8];
  const float* b1  = (const float*)d_in[9];
  const float* W2  = (const float*)d_in[10];
  const float* b2  = (const float*)d_in[11];
  const float* g1  = (const float*)d_in[12];
  const float* be1 = (const float*)d_in[13];
  const float* g2  = (const float*)d_in[14];
  const float* be2 = (const float*)d_in[15];
  const float* Wd  = (const float*)d_in[16];
  const float* bd  = (const float*)d_in[17];
  const float* gd  = (const float*)d_in[18];
  const float* bed = (const float*)d_in[19];
  char* ws = (char*)d_ws;
  // region R0 (lifetime-aliased): src_h f16 [0,64M) -> scores f16 [0,64M) -> x_att f32 [0,32M)
  ushort* src_h = (ushort*)(ws + 0);
  ushort* scores= (ushort*)(ws + 0);
  float*  x_att = (float*) (ws + 0);
  ushort* xnb   = (ushort*)(ws + 67108864);
  ushort* hbuf  = (ushort*)(ws + 83886080);
  // region R1: prob f16 [128,192M) -> x2 f32 [128,160), x2nb [160,176), y [176,192)
  ushort* prob  = (ushort*)(ws + 134217728);
  float*  x2    = (float*) (ws + 134217728);
  ushort* x2nb  = (ushort*)(ws + 167772160);
  float*  y     = (float*) (ws + 184549376);
  // persistent (>=192MiB)
  ushort* Qh    = (ushort*)(ws + 201326592);
  ushort* Kh    = (ushort*)(ws + 218103808);
  ushort* VTh   = (ushort*)(ws + 226492416);
  ushort* WqT   = (ushort*)(ws + 234881024);
  ushort* WvT   = (ushort*)(ws + 243269632);
  ushort* W1T   = (ushort*)(ws + 244318208);
  ushort* W2T   = (ushort*)(ws + 248512512);
  ushort* WdT   = (ushort*)(ws + 252706816);
  float*  ps    = (float*) (ws + 253755392);
  float*  pq    = (float*) (ws + 253886464);
  float*  sc1   = (float*) (ws + 254017536);
  float*  sh1   = (float*) (ws + 254021632);
  float*  sc2   = (float*) (ws + 254025728);
  float*  sh2   = (float*) (ws + 254029824);
  float*  scd   = (float*) (ws + 254033920);
  float*  shd   = (float*) (ws + 254035968);

  // allow 96KB dynamic LDS for the pipelined GEMM
  (void)hipFuncSetAttribute((const void*)k_gemm2<0>, hipFuncAttributeMaxDynamicSharedMemorySize, 98304);
  (void)hipFuncSetAttribute((const void*)k_gemm2<2>, hipFuncAttributeMaxDynamicSharedMemorySize, 98304);
  (void)hipFuncSetAttribute((const void*)k_gemm2<3>, hipFuncAttributeMaxDynamicSharedMemorySize, 98304);
  (void)hipFuncSetAttribute((const void*)k_gemm2<4>, hipFuncAttributeMaxDynamicSharedMemorySize, 98304);
  (void)hipFuncSetAttribute((const void*)k_gemm2<5>, hipFuncAttributeMaxDynamicSharedMemorySize, 98304);

  dim3 b256(256), b512(512);
  k_conv<<<dim3(16384), b256, 0, stream>>>(src, src_h, (long)NSRC*QDIM);
  k_prep<<<dim3(9216), b256, 0, stream>>>(Wq, Wv, W1, W2, Wd, WqT, WvT, W1T, W2T, WdT);
  // Q (pipelined 256x128), K and V^T (legacy, fused f32 A)
  k_gemm2<0><<<dim3(256), b512, 98304, stream>>>(src_h, WqT, NSRC, DM, QDIM, bq, nullptr, 1.f, nullptr, Qh, 7, 3);
  k_gemm<0,true><<<dim3(256), b256, 0, stream>>>(a1, WqT, MANC, DM, QDIM, bq, 1.f, nullptr, Kh, 7, 3);
  k_gemm<1,true><<<dim3(256), b256, 0, stream>>>(a2, WvT, MANC, DM, VDIM, bv, 1.f, nullptr, VTh, 7, 3);
  // scores(f16) = (Q K^T)/32 * label_graph ; softmax(f16) ; x = prob V
  k_gemm2<2><<<dim3(1024), b512, 98304, stream>>>(Qh, Kh, NSRC, MANC, DM, nullptr, lg, 0.03125f, nullptr, scores, 31, 5);
  k_softmax<<<dim3(NSRC), b256, 0, stream>>>(scores, prob);
  k_gemm2<3><<<dim3(256), b512, 98304, stream>>>(prob, VTh, NSRC, DM, MANC, nullptr, nullptr, 1.f/512.f, x_att, nullptr, 7, 3);
  // BN1
  k_bn_partial<<<dim3(DM/256, 32), b256, 0, stream>>>(x_att, ps, pq, DM, NSRC/32);
  k_bn_final<<<dim3(DM/256), b256, 0, stream>>>(ps, pq, g1, be1, sc1, sh1, DM, 1.f/NSRC, 32);
  k_bn_apply<<<dim3(8192), b256, 0, stream>>>(x_att, sc1, sh1, xnb, DM, (long)NSRC*DM);
  // FFN
  k_gemm2<4><<<dim3(512), b512, 98304, stream>>>(xnb, W1T, NSRC, FFD, DM, b1, nullptr, 1.f, nullptr, hbuf, 15, 4);
  k_gemm2<5><<<dim3(256), b512, 98304, stream>>>(hbuf, W2T, NSRC, DM, FFD, b2, xnb, 1.f, x2, nullptr, 7, 3);
  // BN2
  k_bn_partial<<<dim3(DM/256, 32), b256, 0, stream>>>(x2, ps, pq, DM, NSRC/32);
  k_bn_final<<<dim3(DM/256), b256, 0, stream>>>(ps, pq, g2, be2, sc2, sh2, DM, 1.f/NSRC, 32);
  k_bn_apply<<<dim3(8192), b256, 0, stream>>>(x2, sc2, sh2, x2nb, DM, (long)NSRC*DM);
  // decoder + BN + tanh
  k_gemm<6,false><<<dim3(256), b256, 0, stream>>>(x2nb, WdT, NSRC, VDIM, DM, bd, 1.f, y, nullptr, 3, 2);
  k_bn_partial<<<dim3(VDIM/256, 32), b256, 0, stream>>>(y, ps, pq, VDIM, NSRC/32);
  k_bn_final<<<dim3(2), b256, 0, stream>>>(ps, pq, gd, bed, scd, shd, VDIM, 1.f/NSRC, 32);
  k_bn_tanh<<<dim3(4096), b256, 0, stream>>>(y, scd, shd, (float*)d_out, VDIM, (long)NSRC*VDIM);
}

// Round 5
// 781.444 us; speedup vs baseline: 2.6931x; 1.0007x over previous
//
#include <hip/hip_runtime.h>

typedef __attribute__((ext_vector_type(4))) float f32x4;
typedef __attribute__((ext_vector_type(8))) _Float16 f16x8;

#define NSRC 8192
#define MANC 4096
#define QDIM 4096
#define VDIM 512
#define DM   1024
#define FFD  2048

__device__ __forceinline__ ushort f2h(float f){ _Float16 h=(_Float16)f; return __builtin_bit_cast(ushort,h); }
__device__ __forceinline__ float h2f(ushort u){ _Float16 h=__builtin_bit_cast(_Float16,u); return (float)h; }
__device__ __forceinline__ uint pk2(float a,float b){ return (uint)f2h(a) | ((uint)f2h(b)<<16); }

__device__ __forceinline__ void gload16(const ushort* g, ushort* l){
  __builtin_amdgcn_global_load_lds(
    (const __attribute__((address_space(1))) unsigned int*)g,
    (__attribute__((address_space(3))) unsigned int*)l, 16, 0, 0);
}

// ---------- f32 -> f16 convert (src only) ----------
__global__ __launch_bounds__(256) void k_conv(const float* __restrict__ in, ushort* __restrict__ out, long n){
  long i = ((long)blockIdx.x*256 + threadIdx.x)*8;
  if (i >= n) return;
  float4 a = *(const float4*)(in+i);
  float4 b = *(const float4*)(in+i+4);
  uint4 o; o.x=pk2(a.x,a.y); o.y=pk2(a.z,a.w); o.z=pk2(b.x,b.y); o.w=pk2(b.z,b.w);
  *(uint4*)(out+i) = o;
}

// ---------- merged weight transposes: W[K][N] f32 -> WT[N][K] f16 ----------
__device__ __forceinline__ void tr32(const float* __restrict__ W, ushort* __restrict__ WT,
                                     int K, int N, int bx, int by, int tid){
  __shared__ float tile[32][33];
  int n0 = bx*32, k0 = by*32;
  int tx = tid & 31, ty = tid >> 5;
  #pragma unroll
  for (int i=0;i<4;++i) tile[ty+i*8][tx] = W[(long)(k0+ty+i*8)*N + n0+tx];
  __syncthreads();
  #pragma unroll
  for (int i=0;i<4;++i){ int nn=ty+i*8; WT[(long)(n0+nn)*K + k0+tx] = f2h(tile[tx][nn]); }
}
__global__ __launch_bounds__(256) void k_prep(const float* __restrict__ Wq, const float* __restrict__ Wv,
    const float* __restrict__ W1, const float* __restrict__ W2, const float* __restrict__ Wd,
    ushort* __restrict__ WqT, ushort* __restrict__ WvT, ushort* __restrict__ W1T,
    ushort* __restrict__ W2T, ushort* __restrict__ WdT){
  int b = blockIdx.x, t = threadIdx.x;
  if (b < 4096)                 tr32(Wq, WqT, QDIM, DM,  b % 32,        b / 32,        t);
  else if (b < 4608)            tr32(Wv, WvT, VDIM, DM,  (b-4096)%32,   (b-4096)/32,   t);
  else if (b < 6656)            tr32(W1, W1T, DM,  FFD,  (b-4608)%64,   (b-4608)/64,   t);
  else if (b < 8704)            tr32(W2, W2T, FFD, DM,   (b-6656)%32,   (b-6656)/32,   t);
  else                          tr32(Wd, WdT, DM,  VDIM, (b-8704)%16,   (b-8704)/16,   t);
}

// ============ phase-interleaved 256x128 GEMM, 9-slot LDS ring, counted vmcnt ============
// C[M,N] = A[M,K](f16) * Bt[N,K]^T(f16). 512 thr = 8 waves (4M x 2N), 64x64/wave.
// K-tile (BK=64) = 3 half-tiles (A-half0, A-half1, B) of 128x64 f16 = 16KB each.
// Ring: 9 slots x 16KB = 144KB. Tile t uses slots (3t)%9..(3t+2)%9; while computing
// tile t we stage tile t+2 (slots freed by tile t-1). vmcnt(6) once per tile keeps
// tile t+2's 6 loads in flight (lead ~2 K-tiles, covers cold HBM latency).
// 4 phases/tile, 8 MFMA each, one raw s_barrier per phase, setprio around MFMA.
// EPI: 0 f16+bias | 2 f16 *alpha*extra(f32) | 3 f32 *alpha | 4 f16 tanh(+bias) | 5 f32 +bias+extra(f16)
template<int EPI>
__global__ __launch_bounds__(512,1) void k_gemm3(const ushort* __restrict__ A, const ushort* __restrict__ Bt,
    int M, int N, int K, const float* __restrict__ bias, const void* __restrict__ extra,
    float alpha, float* __restrict__ Cf, ushort* __restrict__ Ch, int gxm1, int lg2gx)
{
  extern __shared__ ushort lds[];   // 9 * 8192 shorts
  const int tid = threadIdx.x, lane = tid & 63, w = tid >> 6;
  const int wm = (w >> 1) * 64, wn = (w & 1) * 64;   // wm {0,64,128,192}, wn {0,64}
  int id = blockIdx.x;
  int nid = (id & 7) * ((int)gridDim.x >> 3) + (id >> 3);
  const int m0 = (nid >> lg2gx) * 256, n0 = (nid & gxm1) * 128;
  const int lr = lane & 15, kg = lane >> 4;
  f32x4 acc[4][4] = {};
  const int nkt = K >> 6;           // all call sites have nkt >= 16
  const ushort* Ap = A + (long)m0 * K;
  const ushort* Bp = Bt + (long)n0 * K;
  // staging map: chunk c in [0,1024) per half-tile; row=c>>3, col-chunk=(c&7)^(row&7)
  const int c0 = tid,        r0 = c0 >> 3, cc0 = (c0 & 7) ^ (r0 & 7);
  const int c1 = 512 + tid,  r1 = c1 >> 3, cc1 = (c1 & 7) ^ (r1 & 7);
  auto stageA = [&](int t, int half, int slot){
    long ko = (long)t * 64;
    gload16(Ap + (long)(half*128 + r0)*K + ko + cc0*8, lds + slot*8192 + c0*8);
    gload16(Ap + (long)(half*128 + r1)*K + ko + cc1*8, lds + slot*8192 + c1*8);
  };
  auto stageB = [&](int t, int slot){
    long ko = (long)t * 64;
    gload16(Bp + (long)r0*K + ko + cc0*8, lds + slot*8192 + c0*8);
    gload16(Bp + (long)r1*K + ko + cc1*8, lds + slot*8192 + c1*8);
  };
  // prologue: stage tiles 0 (slots 0,1,2) and 1 (slots 3,4,5)
  stageA(0,0,0); stageA(0,1,1); stageB(0,2);
  stageA(1,0,3); stageA(1,1,4); stageB(1,5);
  asm volatile("s_waitcnt vmcnt(6)" ::: "memory");   // tile 0 landed; tile 1 in flight
  __builtin_amdgcn_sched_barrier(0);
  __builtin_amdgcn_s_barrier();
  __builtin_amdgcn_sched_barrier(0);
  const int arow = wm & 127;        // local row base within A half-slot
  const int ahalf = wm >> 7;        // which A half this wave reads
  int s0 = 0;                       // ring base slot of current tile
  for (int t = 0; t < nkt; ++t){
    int sa = s0 + ahalf; if (sa >= 9) sa -= 9;
    int sb = s0 + 2;     if (sb >= 9) sb -= 9;
    int p  = s0 + 6;     if (p  >= 9) p  -= 9;   // tile t+2 slots p, p1, p2
    int p1 = p + 1;      if (p1 >= 9) p1 -= 9;
    int p2 = p + 2;      if (p2 >= 9) p2 -= 9;
    const ushort* Aslot = lds + sa*8192;
    const ushort* Bslot = lds + sb*8192;
    const bool st = (t + 2) < nkt;
    f16x8 a0[4], a1[4], b0[4], b1[4];
    // ---- phase 0: read ks0 frags ; stage A-half0(t+2) ; MFMA acc[*][0,1] @ks0 ----
    #pragma unroll
    for (int mi=0;mi<4;++mi){ int r = arow + mi*16 + lr; a0[mi] = *(const f16x8*)&Aslot[r*64 + ((kg ^ (r&7))*8)]; }
    #pragma unroll
    for (int ni=0;ni<4;++ni){ int r = wn + ni*16 + lr;  b0[ni] = *(const f16x8*)&Bslot[r*64 + ((kg ^ (r&7))*8)]; }
    if (st) stageA(t+2, 0, p);
    __builtin_amdgcn_sched_barrier(0);
    __builtin_amdgcn_s_setprio(1);
    #pragma unroll
    for (int mi=0;mi<4;++mi){
      acc[mi][0] = __builtin_amdgcn_mfma_f32_16x16x32_f16(a0[mi], b0[0], acc[mi][0], 0,0,0);
      acc[mi][1] = __builtin_amdgcn_mfma_f32_16x16x32_f16(a0[mi], b0[1], acc[mi][1], 0,0,0);
    }
    __builtin_amdgcn_s_setprio(0);
    __builtin_amdgcn_sched_barrier(0);
    __builtin_amdgcn_s_barrier();
    __builtin_amdgcn_sched_barrier(0);
    // ---- phase 1: read ks1 frags ; stage A-half1(t+2) ; MFMA acc[*][2,3] @ks0 ----
    #pragma unroll
    for (int mi=0;mi<4;++mi){ int r = arow + mi*16 + lr; a1[mi] = *(const f16x8*)&Aslot[r*64 + (((4+kg) ^ (r&7))*8)]; }
    #pragma unroll
    for (int ni=0;ni<4;++ni){ int r = wn + ni*16 + lr;  b1[ni] = *(const f16x8*)&Bslot[r*64 + (((4+kg) ^ (r&7))*8)]; }
    if (st) stageA(t+2, 1, p1);
    __builtin_amdgcn_sched_barrier(0);
    __builtin_amdgcn_s_setprio(1);
    #pragma unroll
    for (int mi=0;mi<4;++mi){
      acc[mi][2] = __builtin_amdgcn_mfma_f32_16x16x32_f16(a0[mi], b0[2], acc[mi][2], 0,0,0);
      acc[mi][3] = __builtin_amdgcn_mfma_f32_16x16x32_f16(a0[mi], b0[3], acc[mi][3], 0,0,0);
    }
    __builtin_amdgcn_s_setprio(0);
    __builtin_amdgcn_sched_barrier(0);
    __builtin_amdgcn_s_barrier();
    __builtin_amdgcn_sched_barrier(0);
    // ---- phase 2: stage B(t+2) ; MFMA acc[*][0,1] @ks1 ----
    if (st) stageB(t+2, p2);
    __builtin_amdgcn_sched_barrier(0);
    __builtin_amdgcn_s_setprio(1);
    #pragma unroll
    for (int mi=0;mi<4;++mi){
      acc[mi][0] = __builtin_amdgcn_mfma_f32_16x16x32_f16(a1[mi], b1[0], acc[mi][0], 0,0,0);
      acc[mi][1] = __builtin_amdgcn_mfma_f32_16x16x32_f16(a1[mi], b1[1], acc[mi][1], 0,0,0);
    }
    __builtin_amdgcn_s_setprio(0);
    __builtin_amdgcn_sched_barrier(0);
    __builtin_amdgcn_s_barrier();
    __builtin_amdgcn_sched_barrier(0);
    // ---- phase 3: MFMA acc[*][2,3] @ks1 ; counted vmcnt ----
    __builtin_amdgcn_s_setprio(1);
    #pragma unroll
    for (int mi=0;mi<4;++mi){
      acc[mi][2] = __builtin_amdgcn_mfma_f32_16x16x32_f16(a1[mi], b1[2], acc[mi][2], 0,0,0);
      acc[mi][3] = __builtin_amdgcn_mfma_f32_16x16x32_f16(a1[mi], b1[3], acc[mi][3], 0,0,0);
    }
    __builtin_amdgcn_s_setprio(0);
    if (st)                { asm volatile("s_waitcnt vmcnt(6)" ::: "memory"); }  // tile t+1 landed
    else if (t + 1 < nkt)  { asm volatile("s_waitcnt vmcnt(0)" ::: "memory"); }
    __builtin_amdgcn_sched_barrier(0);
    __builtin_amdgcn_s_barrier();
    __builtin_amdgcn_sched_barrier(0);
    s0 += 3; if (s0 >= 9) s0 -= 9;
  }
  // ---- epilogue: per-wave 64x64 transpose via LDS -> coalesced stores ----
  __syncthreads();
  float* Lw = ((float*)lds) + w*1024;
  #pragma unroll
  for (int mi = 0; mi < 4; ++mi){
    #pragma unroll
    for (int ni = 0; ni < 4; ++ni)
      #pragma unroll
      for (int r = 0; r < 4; ++r)
        Lw[(kg*4+r)*64 + ni*16 + lr] = acc[mi][ni][r];
    __syncthreads();
    #pragma unroll
    for (int tt = 0; tt < 4; ++tt){
      int fi = tt*64 + lane;
      int row16 = fi >> 4, c4 = fi & 15;
      float4 v4 = *(float4*)&Lw[row16*64 + c4*4];
      int row = m0 + wm + mi*16 + row16;
      int col = n0 + wn + c4*4;
      if (EPI==0){
        float4 b4 = *(const float4*)&bias[col];
        ushort4 o; o.x=f2h(v4.x+b4.x); o.y=f2h(v4.y+b4.y); o.z=f2h(v4.z+b4.z); o.w=f2h(v4.w+b4.w);
        *(ushort4*)&Ch[(long)row*N + col] = o;
      } else if (EPI==2){
        float4 e4 = *(const float4*)((const float*)extra + (long)row*N + col);
        ushort4 o; o.x=f2h(v4.x*alpha*e4.x); o.y=f2h(v4.y*alpha*e4.y);
        o.z=f2h(v4.z*alpha*e4.z); o.w=f2h(v4.w*alpha*e4.w);
        *(ushort4*)&Ch[(long)row*N + col] = o;
      } else if (EPI==3){
        float4 o; o.x=v4.x*alpha; o.y=v4.y*alpha; o.z=v4.z*alpha; o.w=v4.w*alpha;
        *(float4*)&Cf[(long)row*N + col] = o;
      } else if (EPI==4){
        float4 b4 = *(const float4*)&bias[col];
        ushort4 o; o.x=f2h(tanhf(v4.x+b4.x)); o.y=f2h(tanhf(v4.y+b4.y));
        o.z=f2h(tanhf(v4.z+b4.z)); o.w=f2h(tanhf(v4.w+b4.w));
        *(ushort4*)&Ch[(long)row*N + col] = o;
      } else if (EPI==5){
        float4 b4 = *(const float4*)&bias[col];
        ushort4 e4 = *(const ushort4*)((const ushort*)extra + (long)row*N + col);
        float4 o; o.x=v4.x+b4.x+h2f(e4.x); o.y=v4.y+b4.y+h2f(e4.y);
        o.z=v4.z+b4.z+h2f(e4.z); o.w=v4.w+b4.w+h2f(e4.w);
        *(float4*)&Cf[(long)row*N + col] = o;
      }
    }
    __syncthreads();
  }
}

// ---------- legacy 128x128 GEMM (for K, V^T, decoder) ----------
// EPI: 0 f16 out +bias | 1 f16 out transposed +bias | 6 f32 out +bias
template<int EPI, bool A32>
__global__ __launch_bounds__(256,2) void k_gemm(const void* __restrict__ Av, const ushort* __restrict__ Bt,
    int M, int N, int K, const float* __restrict__ bias,
    float alpha, float* __restrict__ Cf, ushort* __restrict__ Ch, int gxm1, int lg2gx)
{
  __shared__ ushort As[128*64];
  __shared__ ushort Bs[128*64];
  const int tid = threadIdx.x, lane = tid & 63, w = tid>>6;
  const int wm = (w>>1)*64, wn = (w&1)*64;
  int id = blockIdx.x;
  int nid = (id & 7)*((int)gridDim.x >> 3) + (id >> 3);
  const int m0 = (nid >> lg2gx)*128, n0 = (nid & gxm1)*128;
  const int lr = lane & 15, kg = lane >> 4;
  f32x4 acc[4][4] = {};
  const int nkt = K >> 6;
  const ushort* Ah = (const ushort*)Av + (A32 ? 0 : (long)m0*K);
  const float*  Af = (const float*)Av  + (A32 ? (long)m0*K : 0);
  const ushort* Bp = Bt + (long)n0*K;
  int rowj[4], colj[4];
  #pragma unroll
  for (int j=0;j<4;++j){
    int c = w*256 + j*64 + lane;
    rowj[j] = c>>3; colj[j] = (c&7) ^ (rowj[j]&7);
  }
  float4 pa[4][2];
  if (A32){
    #pragma unroll
    for (int j=0;j<4;++j){
      const float* s = Af + (long)rowj[j]*K + colj[j]*8;
      pa[j][0] = *(const float4*)s; pa[j][1] = *(const float4*)(s+4);
    }
  }
  for (int kt=0; kt<nkt; ++kt){
    __syncthreads();
    long ko = (long)kt*64;
    if (A32){
      #pragma unroll
      for (int j=0;j<4;++j){
        uint4 o; o.x=pk2(pa[j][0].x,pa[j][0].y); o.y=pk2(pa[j][0].z,pa[j][0].w);
        o.z=pk2(pa[j][1].x,pa[j][1].y); o.w=pk2(pa[j][1].z,pa[j][1].w);
        *(uint4*)&As[(w*256 + j*64 + lane)*8] = o;
      }
    } else {
      #pragma unroll
      for (int j=0;j<4;++j)
        gload16(Ah + (long)rowj[j]*K + ko + colj[j]*8, As + (w*4+j)*512);
    }
    #pragma unroll
    for (int j=0;j<4;++j)
      gload16(Bp + (long)rowj[j]*K + ko + colj[j]*8, Bs + (w*4+j)*512);
    __syncthreads();
    if (A32 && kt+1 < nkt){
      long ko2 = ko + 64;
      #pragma unroll
      for (int j=0;j<4;++j){
        const float* s = Af + (long)rowj[j]*K + ko2 + colj[j]*8;
        pa[j][0] = *(const float4*)s; pa[j][1] = *(const float4*)(s+4);
      }
    }
    #pragma unroll
    for (int ks=0; ks<2; ++ks){
      f16x8 af[4], bfr[4];
      #pragma unroll
      for (int mi=0;mi<4;++mi){
        int r = wm + mi*16 + lr, c = ks*4 + kg;
        af[mi] = *(const f16x8*)&As[r*64 + ((c ^ (r&7))*8)];
      }
      #pragma unroll
      for (int ni=0;ni<4;++ni){
        int r = wn + ni*16 + lr, c = ks*4 + kg;
        bfr[ni] = *(const f16x8*)&Bs[r*64 + ((c ^ (r&7))*8)];
      }
      #pragma unroll
      for (int mi=0;mi<4;++mi)
        #pragma unroll
        for (int ni=0;ni<4;++ni)
          acc[mi][ni] = __builtin_amdgcn_mfma_f32_16x16x32_f16(af[mi], bfr[ni], acc[mi][ni], 0,0,0);
    }
  }
  __syncthreads();
  float* Lw = ((float*)As) + w*1024;
  #pragma unroll
  for (int mi=0;mi<4;++mi){
    #pragma unroll
    for (int ni=0;ni<4;++ni)
      #pragma unroll
      for (int r=0;r<4;++r)
        Lw[(kg*4+r)*64 + ni*16 + lr] = acc[mi][ni][r];
    __syncthreads();
    #pragma unroll
    for (int t=0;t<4;++t){
      int fi = t*64 + lane;
      int row16 = fi >> 4, c4 = fi & 15;
      float4 v4 = *(float4*)&Lw[row16*64 + c4*4];
      int row = m0 + wm + mi*16 + row16;
      int col = n0 + wn + c4*4;
      if (EPI==0){
        float4 b4 = *(const float4*)&bias[col];
        ushort4 o; o.x=f2h(v4.x+b4.x); o.y=f2h(v4.y+b4.y); o.z=f2h(v4.z+b4.z); o.w=f2h(v4.w+b4.w);
        *(ushort4*)&Ch[(long)row*N + col] = o;
      } else if (EPI==1){
        float4 b4 = *(const float4*)&bias[col];
        Ch[(long)(col+0)*M + row] = f2h(v4.x+b4.x);
        Ch[(long)(col+1)*M + row] = f2h(v4.y+b4.y);
        Ch[(long)(col+2)*M + row] = f2h(v4.z+b4.z);
        Ch[(long)(col+3)*M + row] = f2h(v4.w+b4.w);
      } else {
        float4 b4 = *(const float4*)&bias[col];
        float4 o; o.x=v4.x+b4.x; o.y=v4.y+b4.y; o.z=v4.z+b4.z; o.w=v4.w+b4.w;
        *(float4*)&Cf[(long)row*N + col] = o;
      }
    }
    __syncthreads();
  }
}

// ---------- row softmax over 4096 f16 cols, writes prob*512 as f16 ----------
__global__ __launch_bounds__(256) void k_softmax(const ushort* __restrict__ S, ushort* __restrict__ P){
  const long base = (long)blockIdx.x * 4096;
  const int t = threadIdx.x;
  uint u[8];
  *(uint4*)&u[0] = *(const uint4*)(S + base + t*16);
  *(uint4*)&u[4] = *(const uint4*)(S + base + t*16 + 8);
  float v[16];
  #pragma unroll
  for (int i=0;i<8;++i){ v[2*i]=h2f((ushort)(u[i]&0xffff)); v[2*i+1]=h2f((ushort)(u[i]>>16)); }
  float mx = -3.4e38f;
  #pragma unroll
  for (int i=0;i<16;++i) mx = fmaxf(mx, v[i]);
  #pragma unroll
  for (int off=1; off<64; off<<=1) mx = fmaxf(mx, __shfl_xor(mx, off));
  __shared__ float red[8];
  int wv = t>>6;
  if ((t&63)==0) red[wv]=mx;
  __syncthreads();
  mx = fmaxf(fmaxf(red[0],red[1]), fmaxf(red[2],red[3]));
  float e[16]; float sum=0.f;
  #pragma unroll
  for (int i=0;i<16;++i){ e[i]=__expf(v[i]-mx); sum+=e[i]; }
  #pragma unroll
  for (int off=1; off<64; off<<=1) sum += __shfl_xor(sum, off);
  if ((t&63)==0) red[4+wv]=sum;
  __syncthreads();
  sum = red[4]+red[5]+red[6]+red[7];
  float s = 512.f/sum;
  uint o[8];
  #pragma unroll
  for (int i=0;i<8;++i) o[i]=pk2(e[2*i]*s, e[2*i+1]*s);
  *(uint4*)(P + base + t*16)     = *(uint4*)&o[0];
  *(uint4*)(P + base + t*16 + 8) = *(uint4*)&o[4];
}

// ---------- batchnorm: partial sums / finalize / apply ----------
__global__ __launch_bounds__(256) void k_bn_partial(const float* __restrict__ X, float* __restrict__ ps, float* __restrict__ pq, int F, int rowsPer){
  int col = blockIdx.x*256 + threadIdx.x;
  long r0 = (long)blockIdx.y * rowsPer;
  float s=0.f,q=0.f;
  for (int r=0;r<rowsPer;++r){ float x = X[(r0+r)*F + col]; s+=x; q+=x*x; }
  ps[(long)blockIdx.y*F + col]=s; pq[(long)blockIdx.y*F + col]=q;
}
__global__ __launch_bounds__(256) void k_bn_final(const float* __restrict__ ps, const float* __restrict__ pq,
    const float* __restrict__ gamma, const float* __restrict__ beta,
    float* __restrict__ scale, float* __restrict__ shift, int F, float invN, int nch){
  int c = blockIdx.x*256 + threadIdx.x;
  if (c>=F) return;
  float s=0.f,q=0.f;
  for (int i=0;i<nch;++i){ s+=ps[i*F+c]; q+=pq[i*F+c]; }
  float mu = s*invN, var = q*invN - mu*mu;
  float sc = gamma[c]*rsqrtf(var+1e-5f);
  scale[c]=sc; shift[c]=beta[c]-mu*sc;
}
__global__ __launch_bounds__(256) void k_bn_apply(const float* __restrict__ X, const float* __restrict__ scale, const float* __restrict__ shift,
    ushort* __restrict__ Xh, int F, long n){
  long i = ((long)blockIdx.x*256 + threadIdx.x)*4;
  if (i>=n) return;
  int c = (int)(i & (long)(F-1));
  float4 x = *(const float4*)(X+i);
  ushort4 o; o.x=f2h(x.x*scale[c]+shift[c]); o.y=f2h(x.y*scale[c+1]+shift[c+1]);
  o.z=f2h(x.z*scale[c+2]+shift[c+2]); o.w=f2h(x.w*scale[c+3]+shift[c+3]);
  *(ushort4*)(Xh+i)=o;
}
__global__ __launch_bounds__(256) void k_bn_tanh(const float* __restrict__ X, const float* __restrict__ scale, const float* __restrict__ shift,
    float* __restrict__ O, int F, long n){
  long i = ((long)blockIdx.x*256 + threadIdx.x)*4;
  if (i>=n) return;
  int c = (int)(i & (long)(F-1));
  float4 x = *(const float4*)(X+i);
  float4 y; y.x=tanhf(x.x*scale[c]+shift[c]); y.y=tanhf(x.y*scale[c+1]+shift[c+1]);
  y.z=tanhf(x.z*scale[c+2]+shift[c+2]); y.w=tanhf(x.w*scale[c+3]+shift[c+3]);
  *(float4*)(O+i)=y;
}

extern "C" void kernel_launch(void* const* d_in, const int* in_sizes, int n_in,
                              void* d_out, int out_size, void* d_ws, size_t ws_size,
                              hipStream_t stream){
  const float* src = (const float*)d_in[0];
  const float* a1  = (const float*)d_in[1];
  const float* a2  = (const float*)d_in[2];
  const float* lg  = (const float*)d_in[3];
  const float* Wq  = (const float*)d_in[4];
  const float* bq  = (const float*)d_in[5];
  const float* Wv  = (const float*)d_in[6];
  const float* bv  = (const float*)d_in[7];
  const float* W1  = (const float*)d_in[8];
  const float* b1  = (const float*)d_in[9];
  const float* W2  = (const float*)d_in[10];
  const float* b2  = (const float*)d_in[11];
  const float* g1  = (const float*)d_in[12];
  const float* be1 = (const float*)d_in[13];
  const float* g2  = (const float*)d_in[14];
  const float* be2 = (const float*)d_in[15];
  const float* Wd  = (const float*)d_in[16];
  const float* bd  = (const float*)d_in[17];
  const float* gd  = (const float*)d_in[18];
  const float* bed = (const float*)d_in[19];
  char* ws = (char*)d_ws;
  // region R0 (lifetime-aliased): src_h f16 [0,64M) -> scores f16 [0,64M) -> x_att f32 [0,32M)
  ushort* src_h = (ushort*)(ws + 0);
  ushort* scores= (ushort*)(ws + 0);
  float*  x_att = (float*) (ws + 0);
  ushort* xnb   = (ushort*)(ws + 67108864);
  ushort* hbuf  = (ushort*)(ws + 83886080);
  // region R1: prob f16 [128,192M) -> x2 f32 [128,160), x2nb [160,176), y [176,192)
  ushort* prob  = (ushort*)(ws + 134217728);
  float*  x2    = (float*) (ws + 134217728);
  ushort* x2nb  = (ushort*)(ws + 167772160);
  float*  y     = (float*) (ws + 184549376);
  // persistent (>=192MiB)
  ushort* Qh    = (ushort*)(ws + 201326592);
  ushort* Kh    = (ushort*)(ws + 218103808);
  ushort* VTh   = (ushort*)(ws + 226492416);
  ushort* WqT   = (ushort*)(ws + 234881024);
  ushort* WvT   = (ushort*)(ws + 243269632);
  ushort* W1T   = (ushort*)(ws + 244318208);
  ushort* W2T   = (ushort*)(ws + 248512512);
  ushort* WdT   = (ushort*)(ws + 252706816);
  float*  ps    = (float*) (ws + 253755392);
  float*  pq    = (float*) (ws + 253886464);
  float*  sc1   = (float*) (ws + 254017536);
  float*  sh1   = (float*) (ws + 254021632);
  float*  sc2   = (float*) (ws + 254025728);
  float*  sh2   = (float*) (ws + 254029824);
  float*  scd   = (float*) (ws + 254033920);
  float*  shd   = (float*) (ws + 254035968);

  // allow 144KB dynamic LDS for the ring GEMM
  (void)hipFuncSetAttribute((const void*)k_gemm3<0>, hipFuncAttributeMaxDynamicSharedMemorySize, 147456);
  (void)hipFuncSetAttribute((const void*)k_gemm3<2>, hipFuncAttributeMaxDynamicSharedMemorySize, 147456);
  (void)hipFuncSetAttribute((const void*)k_gemm3<3>, hipFuncAttributeMaxDynamicSharedMemorySize, 147456);
  (void)hipFuncSetAttribute((const void*)k_gemm3<4>, hipFuncAttributeMaxDynamicSharedMemorySize, 147456);
  (void)hipFuncSetAttribute((const void*)k_gemm3<5>, hipFuncAttributeMaxDynamicSharedMemorySize, 147456);

  dim3 b256(256), b512(512);
  k_conv<<<dim3(16384), b256, 0, stream>>>(src, src_h, (long)NSRC*QDIM);
  k_prep<<<dim3(9216), b256, 0, stream>>>(Wq, Wv, W1, W2, Wd, WqT, WvT, W1T, W2T, WdT);
  // Q (ring 256x128), K and V^T (legacy, fused f32 A)
  k_gemm3<0><<<dim3(256), b512, 147456, stream>>>(src_h, WqT, NSRC, DM, QDIM, bq, nullptr, 1.f, nullptr, Qh, 7, 3);
  k_gemm<0,true><<<dim3(256), b256, 0, stream>>>(a1, WqT, MANC, DM, QDIM, bq, 1.f, nullptr, Kh, 7, 3);
  k_gemm<1,true><<<dim3(256), b256, 0, stream>>>(a2, WvT, MANC, DM, VDIM, bv, 1.f, nullptr, VTh, 7, 3);
  // scores(f16) = (Q K^T)/32 * label_graph ; softmax(f16) ; x = prob V
  k_gemm3<2><<<dim3(1024), b512, 147456, stream>>>(Qh, Kh, NSRC, MANC, DM, nullptr, lg, 0.03125f, nullptr, scores, 31, 5);
  k_softmax<<<dim3(NSRC), b256, 0, stream>>>(scores, prob);
  k_gemm3<3><<<dim3(256), b512, 147456, stream>>>(prob, VTh, NSRC, DM, MANC, nullptr, nullptr, 1.f/512.f, x_att, nullptr, 7, 3);
  // BN1
  k_bn_partial<<<dim3(DM/256, 32), b256, 0, stream>>>(x_att, ps, pq, DM, NSRC/32);
  k_bn_final<<<dim3(DM/256), b256, 0, stream>>>(ps, pq, g1, be1, sc1, sh1, DM, 1.f/NSRC, 32);
  k_bn_apply<<<dim3(8192), b256, 0, stream>>>(x_att, sc1, sh1, xnb, DM, (long)NSRC*DM);
  // FFN
  k_gemm3<4><<<dim3(512), b512, 147456, stream>>>(xnb, W1T, NSRC, FFD, DM, b1, nullptr, 1.f, nullptr, hbuf, 15, 4);
  k_gemm3<5><<<dim3(256), b512, 147456, stream>>>(hbuf, W2T, NSRC, DM, FFD, b2, xnb, 1.f, x2, nullptr, 7, 3);
  // BN2
  k_bn_partial<<<dim3(DM/256, 32), b256, 0, stream>>>(x2, ps, pq, DM, NSRC/32);
  k_bn_final<<<dim3(DM/256), b256, 0, stream>>>(ps, pq, g2, be2, sc2, sh2, DM, 1.f/NSRC, 32);
  k_bn_apply<<<dim3(8192), b256, 0, stream>>>(x2, sc2, sh2, x2nb, DM, (long)NSRC*DM);
  // decoder + BN + tanh
  k_gemm<6,false><<<dim3(256), b256, 0, stream>>>(x2nb, WdT, NSRC, VDIM, DM, bd, 1.f, y, nullptr, 3, 2);
  k_bn_partial<<<dim3(VDIM/256, 32), b256, 0, stream>>>(y, ps, pq, VDIM, NSRC/32);
  k_bn_final<<<dim3(2), b256, 0, stream>>>(ps, pq, gd, bed, scd, shd, VDIM, 1.f/NSRC, 32);
  k_bn_tanh<<<dim3(4096), b256, 0, stream>>>(y, scd, shd, (float*)d_out, VDIM, (long)NSRC*VDIM);
}

// Round 6
// 778.253 us; speedup vs baseline: 2.7041x; 1.0041x over previous
//
#include <hip/hip_runtime.h>

typedef __attribute__((ext_vector_type(4))) float f32x4;
typedef __attribute__((ext_vector_type(8))) _Float16 f16x8;

#define NSRC 8192
#define MANC 4096
#define QDIM 4096
#define VDIM 512
#define DM   1024
#define FFD  2048

__device__ __forceinline__ ushort f2h(float f){ _Float16 h=(_Float16)f; return __builtin_bit_cast(ushort,h); }
__device__ __forceinline__ float h2f(ushort u){ _Float16 h=__builtin_bit_cast(_Float16,u); return (float)h; }
__device__ __forceinline__ uint pk2(float a,float b){ return (uint)f2h(a) | ((uint)f2h(b)<<16); }

__device__ __forceinline__ void gload16(const ushort* g, ushort* l){
  __builtin_amdgcn_global_load_lds(
    (const __attribute__((address_space(1))) unsigned int*)g,
    (__attribute__((address_space(3))) unsigned int*)l, 16, 0, 0);
}

// ---------- f32 -> f16 convert (src only) ----------
__global__ __launch_bounds__(256) void k_conv(const float* __restrict__ in, ushort* __restrict__ out, long n){
  long i = ((long)blockIdx.x*256 + threadIdx.x)*8;
  if (i >= n) return;
  float4 a = *(const float4*)(in+i);
  float4 b = *(const float4*)(in+i+4);
  uint4 o; o.x=pk2(a.x,a.y); o.y=pk2(a.z,a.w); o.z=pk2(b.x,b.y); o.w=pk2(b.z,b.w);
  *(uint4*)(out+i) = o;
}

// ---------- merged weight transposes: W[K][N] f32 -> WT[N][K] f16 ----------
__device__ __forceinline__ void tr32(const float* __restrict__ W, ushort* __restrict__ WT,
                                     int K, int N, int bx, int by, int tid){
  __shared__ float tile[32][33];
  int n0 = bx*32, k0 = by*32;
  int tx = tid & 31, ty = tid >> 5;
  #pragma unroll
  for (int i=0;i<4;++i) tile[ty+i*8][tx] = W[(long)(k0+ty+i*8)*N + n0+tx];
  __syncthreads();
  #pragma unroll
  for (int i=0;i<4;++i){ int nn=ty+i*8; WT[(long)(n0+nn)*K + k0+tx] = f2h(tile[tx][nn]); }
}
__global__ __launch_bounds__(256) void k_prep(const float* __restrict__ Wq, const float* __restrict__ Wv,
    const float* __restrict__ W1, const float* __restrict__ W2, const float* __restrict__ Wd,
    ushort* __restrict__ WqT, ushort* __restrict__ WvT, ushort* __restrict__ W1T,
    ushort* __restrict__ W2T, ushort* __restrict__ WdT){
  int b = blockIdx.x, t = threadIdx.x;
  if (b < 4096)                 tr32(Wq, WqT, QDIM, DM,  b % 32,        b / 32,        t);
  else if (b < 4608)            tr32(Wv, WvT, VDIM, DM,  (b-4096)%32,   (b-4096)/32,   t);
  else if (b < 6656)            tr32(W1, W1T, DM,  FFD,  (b-4608)%64,   (b-4608)/64,   t);
  else if (b < 8704)            tr32(W2, W2T, FFD, DM,   (b-6656)%32,   (b-6656)/32,   t);
  else                          tr32(Wd, WdT, DM,  VDIM, (b-8704)%16,   (b-8704)/16,   t);
}

// ============ m201-phased GEMM: BM=256, BN=256(BIG)/128, 8 waves, 2-phase K-tile ============
// C[M,N] = A[M,K](f16) * Bt[N,K]^T(f16). 512 thr = 8 waves.
// BIG: waves 2Mx4N, per-wave 128x64 out (acc[8][4]); LDS 2x(A 32K + B 32K)=128KB.
// SMALL: waves 4Mx2N, per-wave 64x64 (acc[4][4]);   LDS 2x(A 32K + B 16K)=96KB.
// Per K-tile: phase0 {read ks0 frags; stage ALL of tile t+1; barrier; lgkm(0); MFMA ks0}
//             phase1 {read ks1 frags; barrier; lgkm(0); MFMA ks1; vmcnt(0); barrier}
// Reads issued BEFORE the barrier are consumed AFTER it -> barrier hides LDS latency.
// EPI: 0 f16+bias | 2 f16 *alpha*extra(f32) | 3 f32 *alpha | 4 f16 tanh(+bias) | 5 f32 +bias+extra(f16)
template<int EPI, int BIG>
__global__ __launch_bounds__(512,2) void k_gemmP(const ushort* __restrict__ A, const ushort* __restrict__ Bt,
    int M, int N, int K, const float* __restrict__ bias, const void* __restrict__ extra,
    float alpha, float* __restrict__ Cf, ushort* __restrict__ Ch, int gxm1, int lg2gx)
{
  extern __shared__ ushort lds[];
  constexpr int BN   = BIG ? 256 : 128;
  constexpr int MI   = BIG ? 8 : 4;
  constexpr int BSH  = BIG ? 16384 : 8192;   // shorts per B buffer
  constexpr int HALF = 16384 + BSH;          // shorts per (A,B) buffer pair
  constexpr int BJ   = BIG ? 4 : 2;          // B stage loads per thread
  const int tid = threadIdx.x, lane = tid & 63, w = tid >> 6;
  const int wm = BIG ? (w >> 2) * 128 : (w >> 1) * 64;
  const int wn = BIG ? (w & 3) * 64   : (w & 1) * 64;
  int id = blockIdx.x;
  int nid = (id & 7) * ((int)gridDim.x >> 3) + (id >> 3);
  const int m0 = (nid >> lg2gx) * 256, n0 = (nid & gxm1) * BN;
  const int lr = lane & 15, kg = lane >> 4;
  f32x4 acc[MI][4] = {};
  const int nkt = K >> 6;
  const ushort* Ap = A + (long)m0 * K;
  const ushort* Bp = Bt + (long)n0 * K;
  // staging map: chunk c -> row c>>3, col-chunk (c&7)^(row&7) (XOR swizzle, both sides)
  int rj[4], cj[4];
  #pragma unroll
  for (int j = 0; j < 4; ++j){ int c = j*512 + tid; rj[j] = c >> 3; cj[j] = (c & 7) ^ (rj[j] & 7); }
  // prologue: stage tile 0 into buffer 0
  #pragma unroll
  for (int j = 0; j < 4; ++j)  gload16(Ap + (long)rj[j]*K + cj[j]*8, lds + (j*512 + tid)*8);
  #pragma unroll
  for (int j = 0; j < BJ; ++j) gload16(Bp + (long)rj[j]*K + cj[j]*8, lds + 16384 + (j*512 + tid)*8);
  asm volatile("s_waitcnt vmcnt(0)" ::: "memory");
  __builtin_amdgcn_sched_barrier(0);
  __builtin_amdgcn_s_barrier();
  __builtin_amdgcn_sched_barrier(0);
  int cur = 0;
  for (int t = 0; t < nkt; ++t){
    const ushort* Ab = lds + cur*HALF;
    const ushort* Bb = Ab + 16384;
    ushort* An = lds + (cur^1)*HALF;
    ushort* Bn = An + 16384;
    const bool st = (t + 1) < nkt;
    f16x8 af[MI], bf[4];
    // ---- phase 0 ----
    #pragma unroll
    for (int mi=0;mi<MI;++mi){ int r = wm + mi*16 + lr; af[mi] = *(const f16x8*)&Ab[r*64 + ((kg ^ (r&7))*8)]; }
    #pragma unroll
    for (int ni=0;ni<4;++ni){ int r = wn + ni*16 + lr;  bf[ni] = *(const f16x8*)&Bb[r*64 + ((kg ^ (r&7))*8)]; }
    if (st){
      long ko = (long)(t+1)*64;
      #pragma unroll
      for (int j = 0; j < 4; ++j)  gload16(Ap + (long)rj[j]*K + ko + cj[j]*8, An + (j*512 + tid)*8);
      #pragma unroll
      for (int j = 0; j < BJ; ++j) gload16(Bp + (long)rj[j]*K + ko + cj[j]*8, Bn + (j*512 + tid)*8);
    }
    __builtin_amdgcn_sched_barrier(0);
    __builtin_amdgcn_s_barrier();
    asm volatile("s_waitcnt lgkmcnt(0)" ::: "memory");
    __builtin_amdgcn_sched_barrier(0);
    __builtin_amdgcn_s_setprio(1);
    #pragma unroll
    for (int mi=0;mi<MI;++mi)
      #pragma unroll
      for (int ni=0;ni<4;++ni)
        acc[mi][ni] = __builtin_amdgcn_mfma_f32_16x16x32_f16(af[mi], bf[ni], acc[mi][ni], 0,0,0);
    __builtin_amdgcn_s_setprio(0);
    __builtin_amdgcn_sched_barrier(0);
    // ---- phase 1 ----
    #pragma unroll
    for (int mi=0;mi<MI;++mi){ int r = wm + mi*16 + lr; af[mi] = *(const f16x8*)&Ab[r*64 + (((4+kg) ^ (r&7))*8)]; }
    #pragma unroll
    for (int ni=0;ni<4;++ni){ int r = wn + ni*16 + lr;  bf[ni] = *(const f16x8*)&Bb[r*64 + (((4+kg) ^ (r&7))*8)]; }
    __builtin_amdgcn_sched_barrier(0);
    __builtin_amdgcn_s_barrier();
    asm volatile("s_waitcnt lgkmcnt(0)" ::: "memory");
    __builtin_amdgcn_sched_barrier(0);
    __builtin_amdgcn_s_setprio(1);
    #pragma unroll
    for (int mi=0;mi<MI;++mi)
      #pragma unroll
      for (int ni=0;ni<4;++ni)
        acc[mi][ni] = __builtin_amdgcn_mfma_f32_16x16x32_f16(af[mi], bf[ni], acc[mi][ni], 0,0,0);
    __builtin_amdgcn_s_setprio(0);
    if (st) { asm volatile("s_waitcnt vmcnt(0)" ::: "memory"); }  // t+1 fully staged
    __builtin_amdgcn_sched_barrier(0);
    __builtin_amdgcn_s_barrier();
    __builtin_amdgcn_sched_barrier(0);
    cur ^= 1;
  }
  // ---- epilogue: per-wave LDS transpose -> coalesced stores ----
  __syncthreads();
  float* Lw = ((float*)lds) + w*1024;
  #pragma unroll
  for (int mi = 0; mi < MI; ++mi){
    #pragma unroll
    for (int ni = 0; ni < 4; ++ni)
      #pragma unroll
      for (int r = 0; r < 4; ++r)
        Lw[(kg*4+r)*64 + ni*16 + lr] = acc[mi][ni][r];
    __syncthreads();
    #pragma unroll
    for (int tt = 0; tt < 4; ++tt){
      int fi = tt*64 + lane;
      int row16 = fi >> 4, c4 = fi & 15;
      float4 v4 = *(float4*)&Lw[row16*64 + c4*4];
      int row = m0 + wm + mi*16 + row16;
      int col = n0 + wn + c4*4;
      if (EPI==0){
        float4 b4 = *(const float4*)&bias[col];
        ushort4 o; o.x=f2h(v4.x+b4.x); o.y=f2h(v4.y+b4.y); o.z=f2h(v4.z+b4.z); o.w=f2h(v4.w+b4.w);
        *(ushort4*)&Ch[(long)row*N + col] = o;
      } else if (EPI==2){
        float4 e4 = *(const float4*)((const float*)extra + (long)row*N + col);
        ushort4 o; o.x=f2h(v4.x*alpha*e4.x); o.y=f2h(v4.y*alpha*e4.y);
        o.z=f2h(v4.z*alpha*e4.z); o.w=f2h(v4.w*alpha*e4.w);
        *(ushort4*)&Ch[(long)row*N + col] = o;
      } else if (EPI==3){
        float4 o; o.x=v4.x*alpha; o.y=v4.y*alpha; o.z=v4.z*alpha; o.w=v4.w*alpha;
        *(float4*)&Cf[(long)row*N + col] = o;
      } else if (EPI==4){
        float4 b4 = *(const float4*)&bias[col];
        ushort4 o; o.x=f2h(tanhf(v4.x+b4.x)); o.y=f2h(tanhf(v4.y+b4.y));
        o.z=f2h(tanhf(v4.z+b4.z)); o.w=f2h(tanhf(v4.w+b4.w));
        *(ushort4*)&Ch[(long)row*N + col] = o;
      } else if (EPI==5){
        float4 b4 = *(const float4*)&bias[col];
        ushort4 e4 = *(const ushort4*)((const ushort*)extra + (long)row*N + col);
        float4 o; o.x=v4.x+b4.x+h2f(e4.x); o.y=v4.y+b4.y+h2f(e4.y);
        o.z=v4.z+b4.z+h2f(e4.z); o.w=v4.w+b4.w+h2f(e4.w);
        *(float4*)&Cf[(long)row*N + col] = o;
      }
    }
    __syncthreads();
  }
}

// ---------- legacy 128x128 GEMM (for K, V^T, decoder) ----------
// EPI: 0 f16 out +bias | 1 f16 out transposed +bias | 6 f32 out +bias
template<int EPI, bool A32>
__global__ __launch_bounds__(256,2) void k_gemm(const void* __restrict__ Av, const ushort* __restrict__ Bt,
    int M, int N, int K, const float* __restrict__ bias,
    float alpha, float* __restrict__ Cf, ushort* __restrict__ Ch, int gxm1, int lg2gx)
{
  __shared__ ushort As[128*64];
  __shared__ ushort Bs[128*64];
  const int tid = threadIdx.x, lane = tid & 63, w = tid>>6;
  const int wm = (w>>1)*64, wn = (w&1)*64;
  int id = blockIdx.x;
  int nid = (id & 7)*((int)gridDim.x >> 3) + (id >> 3);
  const int m0 = (nid >> lg2gx)*128, n0 = (nid & gxm1)*128;
  const int lr = lane & 15, kg = lane >> 4;
  f32x4 acc[4][4] = {};
  const int nkt = K >> 6;
  const ushort* Ah = (const ushort*)Av + (A32 ? 0 : (long)m0*K);
  const float*  Af = (const float*)Av  + (A32 ? (long)m0*K : 0);
  const ushort* Bp = Bt + (long)n0*K;
  int rowj[4], colj[4];
  #pragma unroll
  for (int j=0;j<4;++j){
    int c = w*256 + j*64 + lane;
    rowj[j] = c>>3; colj[j] = (c&7) ^ (rowj[j]&7);
  }
  float4 pa[4][2];
  if (A32){
    #pragma unroll
    for (int j=0;j<4;++j){
      const float* s = Af + (long)rowj[j]*K + colj[j]*8;
      pa[j][0] = *(const float4*)s; pa[j][1] = *(const float4*)(s+4);
    }
  }
  for (int kt=0; kt<nkt; ++kt){
    __syncthreads();
    long ko = (long)kt*64;
    if (A32){
      #pragma unroll
      for (int j=0;j<4;++j){
        uint4 o; o.x=pk2(pa[j][0].x,pa[j][0].y); o.y=pk2(pa[j][0].z,pa[j][0].w);
        o.z=pk2(pa[j][1].x,pa[j][1].y); o.w=pk2(pa[j][1].z,pa[j][1].w);
        *(uint4*)&As[(w*256 + j*64 + lane)*8] = o;
      }
    } else {
      #pragma unroll
      for (int j=0;j<4;++j)
        gload16(Ah + (long)rowj[j]*K + ko + colj[j]*8, As + (w*4+j)*512);
    }
    #pragma unroll
    for (int j=0;j<4;++j)
      gload16(Bp + (long)rowj[j]*K + ko + colj[j]*8, Bs + (w*4+j)*512);
    __syncthreads();
    if (A32 && kt+1 < nkt){
      long ko2 = ko + 64;
      #pragma unroll
      for (int j=0;j<4;++j){
        const float* s = Af + (long)rowj[j]*K + ko2 + colj[j]*8;
        pa[j][0] = *(const float4*)s; pa[j][1] = *(const float4*)(s+4);
      }
    }
    #pragma unroll
    for (int ks=0; ks<2; ++ks){
      f16x8 af[4], bfr[4];
      #pragma unroll
      for (int mi=0;mi<4;++mi){
        int r = wm + mi*16 + lr, c = ks*4 + kg;
        af[mi] = *(const f16x8*)&As[r*64 + ((c ^ (r&7))*8)];
      }
      #pragma unroll
      for (int ni=0;ni<4;++ni){
        int r = wn + ni*16 + lr, c = ks*4 + kg;
        bfr[ni] = *(const f16x8*)&Bs[r*64 + ((c ^ (r&7))*8)];
      }
      #pragma unroll
      for (int mi=0;mi<4;++mi)
        #pragma unroll
        for (int ni=0;ni<4;++ni)
          acc[mi][ni] = __builtin_amdgcn_mfma_f32_16x16x32_f16(af[mi], bfr[ni], acc[mi][ni], 0,0,0);
    }
  }
  __syncthreads();
  float* Lw = ((float*)As) + w*1024;
  #pragma unroll
  for (int mi=0;mi<4;++mi){
    #pragma unroll
    for (int ni=0;ni<4;++ni)
      #pragma unroll
      for (int r=0;r<4;++r)
        Lw[(kg*4+r)*64 + ni*16 + lr] = acc[mi][ni][r];
    __syncthreads();
    #pragma unroll
    for (int t=0;t<4;++t){
      int fi = t*64 + lane;
      int row16 = fi >> 4, c4 = fi & 15;
      float4 v4 = *(float4*)&Lw[row16*64 + c4*4];
      int row = m0 + wm + mi*16 + row16;
      int col = n0 + wn + c4*4;
      if (EPI==0){
        float4 b4 = *(const float4*)&bias[col];
        ushort4 o; o.x=f2h(v4.x+b4.x); o.y=f2h(v4.y+b4.y); o.z=f2h(v4.z+b4.z); o.w=f2h(v4.w+b4.w);
        *(ushort4*)&Ch[(long)row*N + col] = o;
      } else if (EPI==1){
        float4 b4 = *(const float4*)&bias[col];
        Ch[(long)(col+0)*M + row] = f2h(v4.x+b4.x);
        Ch[(long)(col+1)*M + row] = f2h(v4.y+b4.y);
        Ch[(long)(col+2)*M + row] = f2h(v4.z+b4.z);
        Ch[(long)(col+3)*M + row] = f2h(v4.w+b4.w);
      } else {
        float4 b4 = *(const float4*)&bias[col];
        float4 o; o.x=v4.x+b4.x; o.y=v4.y+b4.y; o.z=v4.z+b4.z; o.w=v4.w+b4.w;
        *(float4*)&Cf[(long)row*N + col] = o;
      }
    }
    __syncthreads();
  }
}

// ---------- row softmax over 4096 f16 cols, writes prob*512 as f16 ----------
__global__ __launch_bounds__(256) void k_softmax(const ushort* __restrict__ S, ushort* __restrict__ P){
  const long base = (long)blockIdx.x * 4096;
  const int t = threadIdx.x;
  uint u[8];
  *(uint4*)&u[0] = *(const uint4*)(S + base + t*16);
  *(uint4*)&u[4] = *(const uint4*)(S + base + t*16 + 8);
  float v[16];
  #pragma unroll
  for (int i=0;i<8;++i){ v[2*i]=h2f((ushort)(u[i]&0xffff)); v[2*i+1]=h2f((ushort)(u[i]>>16)); }
  float mx = -3.4e38f;
  #pragma unroll
  for (int i=0;i<16;++i) mx = fmaxf(mx, v[i]);
  #pragma unroll
  for (int off=1; off<64; off<<=1) mx = fmaxf(mx, __shfl_xor(mx, off));
  __shared__ float red[8];
  int wv = t>>6;
  if ((t&63)==0) red[wv]=mx;
  __syncthreads();
  mx = fmaxf(fmaxf(red[0],red[1]), fmaxf(red[2],red[3]));
  float e[16]; float sum=0.f;
  #pragma unroll
  for (int i=0;i<16;++i){ e[i]=__expf(v[i]-mx); sum+=e[i]; }
  #pragma unroll
  for (int off=1; off<64; off<<=1) sum += __shfl_xor(sum, off);
  if ((t&63)==0) red[4+wv]=sum;
  __syncthreads();
  sum = red[4]+red[5]+red[6]+red[7];
  float s = 512.f/sum;
  uint o[8];
  #pragma unroll
  for (int i=0;i<8;++i) o[i]=pk2(e[2*i]*s, e[2*i+1]*s);
  *(uint4*)(P + base + t*16)     = *(uint4*)&o[0];
  *(uint4*)(P + base + t*16 + 8) = *(uint4*)&o[4];
}

// ---------- batchnorm: partial sums / finalize / apply ----------
__global__ __launch_bounds__(256) void k_bn_partial(const float* __restrict__ X, float* __restrict__ ps, float* __restrict__ pq, int F, int rowsPer){
  int col = blockIdx.x*256 + threadIdx.x;
  long r0 = (long)blockIdx.y * rowsPer;
  float s=0.f,q=0.f;
  for (int r=0;r<rowsPer;++r){ float x = X[(r0+r)*F + col]; s+=x; q+=x*x; }
  ps[(long)blockIdx.y*F + col]=s; pq[(long)blockIdx.y*F + col]=q;
}
__global__ __launch_bounds__(256) void k_bn_final(const float* __restrict__ ps, const float* __restrict__ pq,
    const float* __restrict__ gamma, const float* __restrict__ beta,
    float* __restrict__ scale, float* __restrict__ shift, int F, float invN, int nch){
  int c = blockIdx.x*256 + threadIdx.x;
  if (c>=F) return;
  float s=0.f,q=0.f;
  for (int i=0;i<nch;++i){ s+=ps[i*F+c]; q+=pq[i*F+c]; }
  float mu = s*invN, var = q*invN - mu*mu;
  float sc = gamma[c]*rsqrtf(var+1e-5f);
  scale[c]=sc; shift[c]=beta[c]-mu*sc;
}
__global__ __launch_bounds__(256) void k_bn_apply(const float* __restrict__ X, const float* __restrict__ scale, const float* __restrict__ shift,
    ushort* __restrict__ Xh, int F, long n){
  long i = ((long)blockIdx.x*256 + threadIdx.x)*4;
  if (i>=n) return;
  int c = (int)(i & (long)(F-1));
  float4 x = *(const float4*)(X+i);
  ushort4 o; o.x=f2h(x.x*scale[c]+shift[c]); o.y=f2h(x.y*scale[c+1]+shift[c+1]);
  o.z=f2h(x.z*scale[c+2]+shift[c+2]); o.w=f2h(x.w*scale[c+3]+shift[c+3]);
  *(ushort4*)(Xh+i)=o;
}
__global__ __launch_bounds__(256) void k_bn_tanh(const float* __restrict__ X, const float* __restrict__ scale, const float* __restrict__ shift,
    float* __restrict__ O, int F, long n){
  long i = ((long)blockIdx.x*256 + threadIdx.x)*4;
  if (i>=n) return;
  int c = (int)(i & (long)(F-1));
  float4 x = *(const float4*)(X+i);
  float4 y; y.x=tanhf(x.x*scale[c]+shift[c]); y.y=tanhf(x.y*scale[c+1]+shift[c+1]);
  y.z=tanhf(x.z*scale[c+2]+shift[c+2]); y.w=tanhf(x.w*scale[c+3]+shift[c+3]);
  *(float4*)(O+i)=y;
}

extern "C" void kernel_launch(void* const* d_in, const int* in_sizes, int n_in,
                              void* d_out, int out_size, void* d_ws, size_t ws_size,
                              hipStream_t stream){
  const float* src = (const float*)d_in[0];
  const float* a1  = (const float*)d_in[1];
  const float* a2  = (const float*)d_in[2];
  const float* lg  = (const float*)d_in[3];
  const float* Wq  = (const float*)d_in[4];
  const float* bq  = (const float*)d_in[5];
  const float* Wv  = (const float*)d_in[6];
  const float* bv  = (const float*)d_in[7];
  const float* W1  = (const float*)d_in[8];
  const float* b1  = (const float*)d_in[9];
  const float* W2  = (const float*)d_in[10];
  const float* b2  = (const float*)d_in[11];
  const float* g1  = (const float*)d_in[12];
  const float* be1 = (const float*)d_in[13];
  const float* g2  = (const float*)d_in[14];
  const float* be2 = (const float*)d_in[15];
  const float* Wd  = (const float*)d_in[16];
  const float* bd  = (const float*)d_in[17];
  const float* gd  = (const float*)d_in[18];
  const float* bed = (const float*)d_in[19];
  char* ws = (char*)d_ws;
  // region R0 (lifetime-aliased): src_h f16 [0,64M) -> scores f16 [0,64M) -> x_att f32 [0,32M)
  ushort* src_h = (ushort*)(ws + 0);
  ushort* scores= (ushort*)(ws + 0);
  float*  x_att = (float*) (ws + 0);
  ushort* xnb   = (ushort*)(ws + 67108864);
  ushort* hbuf  = (ushort*)(ws + 83886080);
  // region R1: prob f16 [128,192M) -> x2 f32 [128,160), x2nb [160,176), y [176,192)
  ushort* prob  = (ushort*)(ws + 134217728);
  float*  x2    = (float*) (ws + 134217728);
  ushort* x2nb  = (ushort*)(ws + 167772160);
  float*  y     = (float*) (ws + 184549376);
  // persistent (>=192MiB)
  ushort* Qh    = (ushort*)(ws + 201326592);
  ushort* Kh    = (ushort*)(ws + 218103808);
  ushort* VTh   = (ushort*)(ws + 226492416);
  ushort* WqT   = (ushort*)(ws + 234881024);
  ushort* WvT   = (ushort*)(ws + 243269632);
  ushort* W1T   = (ushort*)(ws + 244318208);
  ushort* W2T   = (ushort*)(ws + 248512512);
  ushort* WdT   = (ushort*)(ws + 252706816);
  float*  ps    = (float*) (ws + 253755392);
  float*  pq    = (float*) (ws + 253886464);
  float*  sc1   = (float*) (ws + 254017536);
  float*  sh1   = (float*) (ws + 254021632);
  float*  sc2   = (float*) (ws + 254025728);
  float*  sh2   = (float*) (ws + 254029824);
  float*  scd   = (float*) (ws + 254033920);
  float*  shd   = (float*) (ws + 254035968);

  (void)hipFuncSetAttribute((const void*)k_gemmP<0,0>, hipFuncAttributeMaxDynamicSharedMemorySize, 98304);
  (void)hipFuncSetAttribute((const void*)k_gemmP<3,0>, hipFuncAttributeMaxDynamicSharedMemorySize, 98304);
  (void)hipFuncSetAttribute((const void*)k_gemmP<5,0>, hipFuncAttributeMaxDynamicSharedMemorySize, 98304);
  (void)hipFuncSetAttribute((const void*)k_gemmP<2,1>, hipFuncAttributeMaxDynamicSharedMemorySize, 131072);
  (void)hipFuncSetAttribute((const void*)k_gemmP<4,1>, hipFuncAttributeMaxDynamicSharedMemorySize, 131072);

  dim3 b256(256), b512(512);
  k_conv<<<dim3(16384), b256, 0, stream>>>(src, src_h, (long)NSRC*QDIM);
  k_prep<<<dim3(9216), b256, 0, stream>>>(Wq, Wv, W1, W2, Wd, WqT, WvT, W1T, W2T, WdT);
  // Q (SMALL phased), K and V^T (legacy, fused f32 A)
  k_gemmP<0,0><<<dim3(256), b512, 98304, stream>>>(src_h, WqT, NSRC, DM, QDIM, bq, nullptr, 1.f, nullptr, Qh, 7, 3);
  k_gemm<0,true><<<dim3(256), b256, 0, stream>>>(a1, WqT, MANC, DM, QDIM, bq, 1.f, nullptr, Kh, 7, 3);
  k_gemm<1,true><<<dim3(256), b256, 0, stream>>>(a2, WvT, MANC, DM, VDIM, bv, 1.f, nullptr, VTh, 7, 3);
  // scores(f16) = (Q K^T)/32 * label_graph ; softmax(f16) ; x = prob V
  k_gemmP<2,1><<<dim3(512), b512, 131072, stream>>>(Qh, Kh, NSRC, MANC, DM, nullptr, lg, 0.03125f, nullptr, scores, 15, 4);
  k_softmax<<<dim3(NSRC), b256, 0, stream>>>(scores, prob);
  k_gemmP<3,0><<<dim3(256), b512, 98304, stream>>>(prob, VTh, NSRC, DM, MANC, nullptr, nullptr, 1.f/512.f, x_att, nullptr, 7, 3);
  // BN1
  k_bn_partial<<<dim3(DM/256, 32), b256, 0, stream>>>(x_att, ps, pq, DM, NSRC/32);
  k_bn_final<<<dim3(DM/256), b256, 0, stream>>>(ps, pq, g1, be1, sc1, sh1, DM, 1.f/NSRC, 32);
  k_bn_apply<<<dim3(8192), b256, 0, stream>>>(x_att, sc1, sh1, xnb, DM, (long)NSRC*DM);
  // FFN
  k_gemmP<4,1><<<dim3(256), b512, 131072, stream>>>(xnb, W1T, NSRC, FFD, DM, b1, nullptr, 1.f, nullptr, hbuf, 7, 3);
  k_gemmP<5,0><<<dim3(256), b512, 98304, stream>>>(hbuf, W2T, NSRC, DM, FFD, b2, xnb, 1.f, x2, nullptr, 7, 3);
  // BN2
  k_bn_partial<<<dim3(DM/256, 32), b256, 0, stream>>>(x2, ps, pq, DM, NSRC/32);
  k_bn_final<<<dim3(DM/256), b256, 0, stream>>>(ps, pq, g2, be2, sc2, sh2, DM, 1.f/NSRC, 32);
  k_bn_apply<<<dim3(8192), b256, 0, stream>>>(x2, sc2, sh2, x2nb, DM, (long)NSRC*DM);
  // decoder + BN + tanh
  k_gemm<6,false><<<dim3(256), b256, 0, stream>>>(x2nb, WdT, NSRC, VDIM, DM, bd, 1.f, y, nullptr, 3, 2);
  k_bn_partial<<<dim3(VDIM/256, 32), b256, 0, stream>>>(y, ps, pq, VDIM, NSRC/32);
  k_bn_final<<<dim3(2), b256, 0, stream>>>(ps, pq, gd, bed, scd, shd, VDIM, 1.f/NSRC, 32);
  k_bn_tanh<<<dim3(4096), b256, 0, stream>>>(y, scd, shd, (float*)d_out, VDIM, (long)NSRC*VDIM);
}

// Round 7
// 777.638 us; speedup vs baseline: 2.7063x; 1.0008x over previous
//
#include <hip/hip_runtime.h>

typedef __attribute__((ext_vector_type(4))) float f32x4;
typedef __attribute__((ext_vector_type(8))) _Float16 f16x8;

#define NSRC 8192
#define MANC 4096
#define QDIM 4096
#define VDIM 512
#define DM   1024
#define FFD  2048

__device__ __forceinline__ ushort f2h(float f){ _Float16 h=(_Float16)f; return __builtin_bit_cast(ushort,h); }
__device__ __forceinline__ float h2f(ushort u){ _Float16 h=__builtin_bit_cast(_Float16,u); return (float)h; }
__device__ __forceinline__ uint pk2(float a,float b){ return (uint)f2h(a) | ((uint)f2h(b)<<16); }

__device__ __forceinline__ void gload16(const ushort* g, ushort* l){
  __builtin_amdgcn_global_load_lds(
    (const __attribute__((address_space(1))) unsigned int*)g,
    (__attribute__((address_space(3))) unsigned int*)l, 16, 0, 0);
}

// ---------- f32 -> f16 convert (src only) ----------
__global__ __launch_bounds__(256) void k_conv(const float* __restrict__ in, ushort* __restrict__ out, long n){
  long i = ((long)blockIdx.x*256 + threadIdx.x)*8;
  if (i >= n) return;
  float4 a = *(const float4*)(in+i);
  float4 b = *(const float4*)(in+i+4);
  uint4 o; o.x=pk2(a.x,a.y); o.y=pk2(a.z,a.w); o.z=pk2(b.x,b.y); o.w=pk2(b.z,b.w);
  *(uint4*)(out+i) = o;
}

// ---------- merged weight transposes: W[K][N] f32 -> WT[N][K] f16 ----------
__device__ __forceinline__ void tr32(const float* __restrict__ W, ushort* __restrict__ WT,
                                     int K, int N, int bx, int by, int tid){
  __shared__ float tile[32][33];
  int n0 = bx*32, k0 = by*32;
  int tx = tid & 31, ty = tid >> 5;
  #pragma unroll
  for (int i=0;i<4;++i) tile[ty+i*8][tx] = W[(long)(k0+ty+i*8)*N + n0+tx];
  __syncthreads();
  #pragma unroll
  for (int i=0;i<4;++i){ int nn=ty+i*8; WT[(long)(n0+nn)*K + k0+tx] = f2h(tile[tx][nn]); }
}
__global__ __launch_bounds__(256) void k_prep(const float* __restrict__ Wq, const float* __restrict__ Wv,
    const float* __restrict__ W1, const float* __restrict__ W2, const float* __restrict__ Wd,
    ushort* __restrict__ WqT, ushort* __restrict__ WvT, ushort* __restrict__ W1T,
    ushort* __restrict__ W2T, ushort* __restrict__ WdT){
  int b = blockIdx.x, t = threadIdx.x;
  if (b < 4096)                 tr32(Wq, WqT, QDIM, DM,  b % 32,        b / 32,        t);
  else if (b < 4608)            tr32(Wv, WvT, VDIM, DM,  (b-4096)%32,   (b-4096)/32,   t);
  else if (b < 6656)            tr32(W1, W1T, DM,  FFD,  (b-4608)%64,   (b-4608)/64,   t);
  else if (b < 8704)            tr32(W2, W2T, FFD, DM,   (b-6656)%32,   (b-6656)/32,   t);
  else                          tr32(Wd, WdT, DM,  VDIM, (b-8704)%16,   (b-8704)/16,   t);
}

// ============ ring-3 256x128 GEMM: counted vmcnt, compiler-scheduled body ============
// C[M,N] = A[M,K](f16) * Bt[N,K]^T(f16). 512 thr = 8 waves (4M x 2N), 64x64 out/wave.
// LDS ring: 3 slots x (A 32KB + B 16KB) = 144KB. Tile t reads slot t%3; during tile t
// we issue stage of tile t+2 into slot (t+2)%3 (freed by tile t-1; safe after the
// boundary barrier). ONE barrier + ONE counted vmcnt(6) per K-tile; no mid-tile
// barriers, no read pinning -- compiler interleaves ds_read(ks1) with MFMA(ks0).
// vmcnt ledger (FIFO, 6 loads/thread/tile): at boundary after tile t the 6 newest
// are t+2's -> vmcnt(6) certifies tile t+1 fully staged. Prologue: stage t0,t1,
// vmcnt(6) certifies t0.
// EPI: 0 f16+bias | 2 f16 *alpha*extra(f32) | 3 f32 *alpha | 4 f16 tanh(+bias) | 5 f32 +bias+extra(f16)
template<int EPI>
__global__ __launch_bounds__(512,1) void k_gemmR(const ushort* __restrict__ A, const ushort* __restrict__ Bt,
    int M, int N, int K, const float* __restrict__ bias, const void* __restrict__ extra,
    float alpha, float* __restrict__ Cf, ushort* __restrict__ Ch, int gxm1, int lg2gx)
{
  extern __shared__ ushort lds[];        // 3 * 24576 shorts = 144KB
  const int tid = threadIdx.x, lane = tid & 63, w = tid >> 6;
  const int wm = (w >> 1) * 64, wn = (w & 1) * 64;
  int id = blockIdx.x;
  int nid = (id & 7) * ((int)gridDim.x >> 3) + (id >> 3);
  const int m0 = (nid >> lg2gx) * 256, n0 = (nid & gxm1) * 128;
  const int lr = lane & 15, kg = lane >> 4;
  f32x4 acc[4][4] = {};
  const int nkt = K >> 6;                // >= 16 at all call sites
  const ushort* Ap = A + (long)m0 * K;
  const ushort* Bp = Bt + (long)n0 * K;
  // staging map: chunk c -> row c>>3, col-chunk (c&7)^(row&7) (XOR swizzle both sides)
  int rj[4], cj[4];
  #pragma unroll
  for (int j = 0; j < 4; ++j){ int c = j*512 + tid; rj[j] = c >> 3; cj[j] = (c & 7) ^ (rj[j] & 7); }
  auto stage = [&](int t, int slot){
    long ko = (long)t * 64;
    ushort* As = lds + slot*24576;
    ushort* Bs = As + 16384;
    #pragma unroll
    for (int j = 0; j < 4; ++j) gload16(Ap + (long)rj[j]*K + ko + cj[j]*8, As + (j*512 + tid)*8);
    #pragma unroll
    for (int j = 0; j < 2; ++j) gload16(Bp + (long)rj[j]*K + ko + cj[j]*8, Bs + (j*512 + tid)*8);
  };
  // prologue: stage tiles 0 and 1
  stage(0, 0);
  stage(1, 1);
  asm volatile("s_waitcnt vmcnt(6)" ::: "memory");   // tile 0 landed
  __builtin_amdgcn_sched_barrier(0);
  __builtin_amdgcn_s_barrier();
  __builtin_amdgcn_sched_barrier(0);
  int cs = 0;                                        // current slot
  for (int t = 0; t < nkt; ++t){
    int s2 = cs + 2; if (s2 >= 3) s2 -= 3;
    const bool st = (t + 2) < nkt;
    if (st) stage(t + 2, s2);                        // earliest possible issue
    const ushort* Ab = lds + cs*24576;
    const ushort* Bb = Ab + 16384;
    f16x8 a0[4], a1[4], b0[4], b1[4];
    #pragma unroll
    for (int mi=0;mi<4;++mi){
      int r = wm + mi*16 + lr;
      a0[mi] = *(const f16x8*)&Ab[r*64 + ((kg     ^ (r&7))*8)];
      a1[mi] = *(const f16x8*)&Ab[r*64 + (((4+kg) ^ (r&7))*8)];
    }
    #pragma unroll
    for (int ni=0;ni<4;++ni){
      int r = wn + ni*16 + lr;
      b0[ni] = *(const f16x8*)&Bb[r*64 + ((kg     ^ (r&7))*8)];
      b1[ni] = *(const f16x8*)&Bb[r*64 + (((4+kg) ^ (r&7))*8)];
    }
    __builtin_amdgcn_s_setprio(1);
    #pragma unroll
    for (int mi=0;mi<4;++mi)
      #pragma unroll
      for (int ni=0;ni<4;++ni)
        acc[mi][ni] = __builtin_amdgcn_mfma_f32_16x16x32_f16(a0[mi], b0[ni], acc[mi][ni], 0,0,0);
    #pragma unroll
    for (int mi=0;mi<4;++mi)
      #pragma unroll
      for (int ni=0;ni<4;++ni)
        acc[mi][ni] = __builtin_amdgcn_mfma_f32_16x16x32_f16(a1[mi], b1[ni], acc[mi][ni], 0,0,0);
    __builtin_amdgcn_s_setprio(0);
    // boundary: certify tile t+1 staged (counted -- never drain in steady state)
    if (st)               { asm volatile("s_waitcnt vmcnt(6)" ::: "memory"); }
    else if (t + 1 < nkt) { asm volatile("s_waitcnt vmcnt(0)" ::: "memory"); }
    else                  { asm volatile("" ::: "memory"); }
    __builtin_amdgcn_sched_barrier(0);
    __builtin_amdgcn_s_barrier();
    __builtin_amdgcn_sched_barrier(0);
    cs += 1; if (cs >= 3) cs -= 3;
  }
  // ---- epilogue: per-wave 64x64 transpose via LDS -> coalesced stores ----
  __syncthreads();
  float* Lw = ((float*)lds) + w*1024;
  #pragma unroll
  for (int mi = 0; mi < 4; ++mi){
    #pragma unroll
    for (int ni = 0; ni < 4; ++ni)
      #pragma unroll
      for (int r = 0; r < 4; ++r)
        Lw[(kg*4+r)*64 + ni*16 + lr] = acc[mi][ni][r];
    __syncthreads();
    #pragma unroll
    for (int tt = 0; tt < 4; ++tt){
      int fi = tt*64 + lane;
      int row16 = fi >> 4, c4 = fi & 15;
      float4 v4 = *(float4*)&Lw[row16*64 + c4*4];
      int row = m0 + wm + mi*16 + row16;
      int col = n0 + wn + c4*4;
      if (EPI==0){
        float4 b4 = *(const float4*)&bias[col];
        ushort4 o; o.x=f2h(v4.x+b4.x); o.y=f2h(v4.y+b4.y); o.z=f2h(v4.z+b4.z); o.w=f2h(v4.w+b4.w);
        *(ushort4*)&Ch[(long)row*N + col] = o;
      } else if (EPI==2){
        float4 e4 = *(const float4*)((const float*)extra + (long)row*N + col);
        ushort4 o; o.x=f2h(v4.x*alpha*e4.x); o.y=f2h(v4.y*alpha*e4.y);
        o.z=f2h(v4.z*alpha*e4.z); o.w=f2h(v4.w*alpha*e4.w);
        *(ushort4*)&Ch[(long)row*N + col] = o;
      } else if (EPI==3){
        float4 o; o.x=v4.x*alpha; o.y=v4.y*alpha; o.z=v4.z*alpha; o.w=v4.w*alpha;
        *(float4*)&Cf[(long)row*N + col] = o;
      } else if (EPI==4){
        float4 b4 = *(const float4*)&bias[col];
        ushort4 o; o.x=f2h(tanhf(v4.x+b4.x)); o.y=f2h(tanhf(v4.y+b4.y));
        o.z=f2h(tanhf(v4.z+b4.z)); o.w=f2h(tanhf(v4.w+b4.w));
        *(ushort4*)&Ch[(long)row*N + col] = o;
      } else if (EPI==5){
        float4 b4 = *(const float4*)&bias[col];
        ushort4 e4 = *(const ushort4*)((const ushort*)extra + (long)row*N + col);
        float4 o; o.x=v4.x+b4.x+h2f(e4.x); o.y=v4.y+b4.y+h2f(e4.y);
        o.z=v4.z+b4.z+h2f(e4.z); o.w=v4.w+b4.w+h2f(e4.w);
        *(float4*)&Cf[(long)row*N + col] = o;
      }
    }
    __syncthreads();
  }
}

// ---------- legacy 128x128 GEMM (for K, V^T, decoder) ----------
// EPI: 0 f16 out +bias | 1 f16 out transposed +bias | 6 f32 out +bias
template<int EPI, bool A32>
__global__ __launch_bounds__(256,2) void k_gemm(const void* __restrict__ Av, const ushort* __restrict__ Bt,
    int M, int N, int K, const float* __restrict__ bias,
    float alpha, float* __restrict__ Cf, ushort* __restrict__ Ch, int gxm1, int lg2gx)
{
  __shared__ ushort As[128*64];
  __shared__ ushort Bs[128*64];
  const int tid = threadIdx.x, lane = tid & 63, w = tid>>6;
  const int wm = (w>>1)*64, wn = (w&1)*64;
  int id = blockIdx.x;
  int nid = (id & 7)*((int)gridDim.x >> 3) + (id >> 3);
  const int m0 = (nid >> lg2gx)*128, n0 = (nid & gxm1)*128;
  const int lr = lane & 15, kg = lane >> 4;
  f32x4 acc[4][4] = {};
  const int nkt = K >> 6;
  const ushort* Ah = (const ushort*)Av + (A32 ? 0 : (long)m0*K);
  const float*  Af = (const float*)Av  + (A32 ? (long)m0*K : 0);
  const ushort* Bp = Bt + (long)n0*K;
  int rowj[4], colj[4];
  #pragma unroll
  for (int j=0;j<4;++j){
    int c = w*256 + j*64 + lane;
    rowj[j] = c>>3; colj[j] = (c&7) ^ (rowj[j]&7);
  }
  float4 pa[4][2];
  if (A32){
    #pragma unroll
    for (int j=0;j<4;++j){
      const float* s = Af + (long)rowj[j]*K + colj[j]*8;
      pa[j][0] = *(const float4*)s; pa[j][1] = *(const float4*)(s+4);
    }
  }
  for (int kt=0; kt<nkt; ++kt){
    __syncthreads();
    long ko = (long)kt*64;
    if (A32){
      #pragma unroll
      for (int j=0;j<4;++j){
        uint4 o; o.x=pk2(pa[j][0].x,pa[j][0].y); o.y=pk2(pa[j][0].z,pa[j][0].w);
        o.z=pk2(pa[j][1].x,pa[j][1].y); o.w=pk2(pa[j][1].z,pa[j][1].w);
        *(uint4*)&As[(w*256 + j*64 + lane)*8] = o;
      }
    } else {
      #pragma unroll
      for (int j=0;j<4;++j)
        gload16(Ah + (long)rowj[j]*K + ko + colj[j]*8, As + (w*4+j)*512);
    }
    #pragma unroll
    for (int j=0;j<4;++j)
      gload16(Bp + (long)rowj[j]*K + ko + colj[j]*8, Bs + (w*4+j)*512);
    __syncthreads();
    if (A32 && kt+1 < nkt){
      long ko2 = ko + 64;
      #pragma unroll
      for (int j=0;j<4;++j){
        const float* s = Af + (long)rowj[j]*K + ko2 + colj[j]*8;
        pa[j][0] = *(const float4*)s; pa[j][1] = *(const float4*)(s+4);
      }
    }
    #pragma unroll
    for (int ks=0; ks<2; ++ks){
      f16x8 af[4], bfr[4];
      #pragma unroll
      for (int mi=0;mi<4;++mi){
        int r = wm + mi*16 + lr, c = ks*4 + kg;
        af[mi] = *(const f16x8*)&As[r*64 + ((c ^ (r&7))*8)];
      }
      #pragma unroll
      for (int ni=0;ni<4;++ni){
        int r = wn + ni*16 + lr, c = ks*4 + kg;
        bfr[ni] = *(const f16x8*)&Bs[r*64 + ((c ^ (r&7))*8)];
      }
      #pragma unroll
      for (int mi=0;mi<4;++mi)
        #pragma unroll
        for (int ni=0;ni<4;++ni)
          acc[mi][ni] = __builtin_amdgcn_mfma_f32_16x16x32_f16(af[mi], bfr[ni], acc[mi][ni], 0,0,0);
    }
  }
  __syncthreads();
  float* Lw = ((float*)As) + w*1024;
  #pragma unroll
  for (int mi=0;mi<4;++mi){
    #pragma unroll
    for (int ni=0;ni<4;++ni)
      #pragma unroll
      for (int r=0;r<4;++r)
        Lw[(kg*4+r)*64 + ni*16 + lr] = acc[mi][ni][r];
    __syncthreads();
    #pragma unroll
    for (int t=0;t<4;++t){
      int fi = t*64 + lane;
      int row16 = fi >> 4, c4 = fi & 15;
      float4 v4 = *(float4*)&Lw[row16*64 + c4*4];
      int row = m0 + wm + mi*16 + row16;
      int col = n0 + wn + c4*4;
      if (EPI==0){
        float4 b4 = *(const float4*)&bias[col];
        ushort4 o; o.x=f2h(v4.x+b4.x); o.y=f2h(v4.y+b4.y); o.z=f2h(v4.z+b4.z); o.w=f2h(v4.w+b4.w);
        *(ushort4*)&Ch[(long)row*N + col] = o;
      } else if (EPI==1){
        float4 b4 = *(const float4*)&bias[col];
        Ch[(long)(col+0)*M + row] = f2h(v4.x+b4.x);
        Ch[(long)(col+1)*M + row] = f2h(v4.y+b4.y);
        Ch[(long)(col+2)*M + row] = f2h(v4.z+b4.z);
        Ch[(long)(col+3)*M + row] = f2h(v4.w+b4.w);
      } else {
        float4 b4 = *(const float4*)&bias[col];
        float4 o; o.x=v4.x+b4.x; o.y=v4.y+b4.y; o.z=v4.z+b4.z; o.w=v4.w+b4.w;
        *(float4*)&Cf[(long)row*N + col] = o;
      }
    }
    __syncthreads();
  }
}

// ---------- row softmax over 4096 f16 cols, writes prob*512 as f16 ----------
__global__ __launch_bounds__(256) void k_softmax(const ushort* __restrict__ S, ushort* __restrict__ P){
  const long base = (long)blockIdx.x * 4096;
  const int t = threadIdx.x;
  uint u[8];
  *(uint4*)&u[0] = *(const uint4*)(S + base + t*16);
  *(uint4*)&u[4] = *(const uint4*)(S + base + t*16 + 8);
  float v[16];
  #pragma unroll
  for (int i=0;i<8;++i){ v[2*i]=h2f((ushort)(u[i]&0xffff)); v[2*i+1]=h2f((ushort)(u[i]>>16)); }
  float mx = -3.4e38f;
  #pragma unroll
  for (int i=0;i<16;++i) mx = fmaxf(mx, v[i]);
  #pragma unroll
  for (int off=1; off<64; off<<=1) mx = fmaxf(mx, __shfl_xor(mx, off));
  __shared__ float red[8];
  int wv = t>>6;
  if ((t&63)==0) red[wv]=mx;
  __syncthreads();
  mx = fmaxf(fmaxf(red[0],red[1]), fmaxf(red[2],red[3]));
  float e[16]; float sum=0.f;
  #pragma unroll
  for (int i=0;i<16;++i){ e[i]=__expf(v[i]-mx); sum+=e[i]; }
  #pragma unroll
  for (int off=1; off<64; off<<=1) sum += __shfl_xor(sum, off);
  if ((t&63)==0) red[4+wv]=sum;
  __syncthreads();
  sum = red[4]+red[5]+red[6]+red[7];
  float s = 512.f/sum;
  uint o[8];
  #pragma unroll
  for (int i=0;i<8;++i) o[i]=pk2(e[2*i]*s, e[2*i+1]*s);
  *(uint4*)(P + base + t*16)     = *(uint4*)&o[0];
  *(uint4*)(P + base + t*16 + 8) = *(uint4*)&o[4];
}

// ---------- batchnorm: partial sums / finalize / apply ----------
__global__ __launch_bounds__(256) void k_bn_partial(const float* __restrict__ X, float* __restrict__ ps, float* __restrict__ pq, int F, int rowsPer){
  int col = blockIdx.x*256 + threadIdx.x;
  long r0 = (long)blockIdx.y * rowsPer;
  float s=0.f,q=0.f;
  for (int r=0;r<rowsPer;++r){ float x = X[(r0+r)*F + col]; s+=x; q+=x*x; }
  ps[(long)blockIdx.y*F + col]=s; pq[(long)blockIdx.y*F + col]=q;
}
__global__ __launch_bounds__(256) void k_bn_final(const float* __restrict__ ps, const float* __restrict__ pq,
    const float* __restrict__ gamma, const float* __restrict__ beta,
    float* __restrict__ scale, float* __restrict__ shift, int F, float invN, int nch){
  int c = blockIdx.x*256 + threadIdx.x;
  if (c>=F) return;
  float s=0.f,q=0.f;
  for (int i=0;i<nch;++i){ s+=ps[i*F+c]; q+=pq[i*F+c]; }
  float mu = s*invN, var = q*invN - mu*mu;
  float sc = gamma[c]*rsqrtf(var+1e-5f);
  scale[c]=sc; shift[c]=beta[c]-mu*sc;
}
__global__ __launch_bounds__(256) void k_bn_apply(const float* __restrict__ X, const float* __restrict__ scale, const float* __restrict__ shift,
    ushort* __restrict__ Xh, int F, long n){
  long i = ((long)blockIdx.x*256 + threadIdx.x)*4;
  if (i>=n) return;
  int c = (int)(i & (long)(F-1));
  float4 x = *(const float4*)(X+i);
  ushort4 o; o.x=f2h(x.x*scale[c]+shift[c]); o.y=f2h(x.y*scale[c+1]+shift[c+1]);
  o.z=f2h(x.z*scale[c+2]+shift[c+2]); o.w=f2h(x.w*scale[c+3]+shift[c+3]);
  *(ushort4*)(Xh+i)=o;
}
__global__ __launch_bounds__(256) void k_bn_tanh(const float* __restrict__ X, const float* __restrict__ scale, const float* __restrict__ shift,
    float* __restrict__ O, int F, long n){
  long i = ((long)blockIdx.x*256 + threadIdx.x)*4;
  if (i>=n) return;
  int c = (int)(i & (long)(F-1));
  float4 x = *(const float4*)(X+i);
  float4 y; y.x=tanhf(x.x*scale[c]+shift[c]); y.y=tanhf(x.y*scale[c+1]+shift[c+1]);
  y.z=tanhf(x.z*scale[c+2]+shift[c+2]); y.w=tanhf(x.w*scale[c+3]+shift[c+3]);
  *(float4*)(O+i)=y;
}

extern "C" void kernel_launch(void* const* d_in, const int* in_sizes, int n_in,
                              void* d_out, int out_size, void* d_ws, size_t ws_size,
                              hipStream_t stream){
  const float* src = (const float*)d_in[0];
  const float* a1  = (const float*)d_in[1];
  const float* a2  = (const float*)d_in[2];
  const float* lg  = (const float*)d_in[3];
  const float* Wq  = (const float*)d_in[4];
  const float* bq  = (const float*)d_in[5];
  const float* Wv  = (const float*)d_in[6];
  const float* bv  = (const float*)d_in[7];
  const float* W1  = (const float*)d_in[8];
  const float* b1  = (const float*)d_in[9];
  const float* W2  = (const float*)d_in[10];
  const float* b2  = (const float*)d_in[11];
  const float* g1  = (const float*)d_in[12];
  const float* be1 = (const float*)d_in[13];
  const float* g2  = (const float*)d_in[14];
  const float* be2 = (const float*)d_in[15];
  const float* Wd  = (const float*)d_in[16];
  const float* bd  = (const float*)d_in[17];
  const float* gd  = (const float*)d_in[18];
  const float* bed = (const float*)d_in[19];
  char* ws = (char*)d_ws;
  // region R0 (lifetime-aliased): src_h f16 [0,64M) -> scores f16 [0,64M) -> x_att f32 [0,32M)
  ushort* src_h = (ushort*)(ws + 0);
  ushort* scores= (ushort*)(ws + 0);
  float*  x_att = (float*) (ws + 0);
  ushort* xnb   = (ushort*)(ws + 67108864);
  ushort* hbuf  = (ushort*)(ws + 83886080);
  // region R1: prob f16 [128,192M) -> x2 f32 [128,160), x2nb [160,176), y [176,192)
  ushort* prob  = (ushort*)(ws + 134217728);
  float*  x2    = (float*) (ws + 134217728);
  ushort* x2nb  = (ushort*)(ws + 167772160);
  float*  y     = (float*) (ws + 184549376);
  // persistent (>=192MiB)
  ushort* Qh    = (ushort*)(ws + 201326592);
  ushort* Kh    = (ushort*)(ws + 218103808);
  ushort* VTh   = (ushort*)(ws + 226492416);
  ushort* WqT   = (ushort*)(ws + 234881024);
  ushort* WvT   = (ushort*)(ws + 243269632);
  ushort* W1T   = (ushort*)(ws + 244318208);
  ushort* W2T   = (ushort*)(ws + 248512512);
  ushort* WdT   = (ushort*)(ws + 252706816);
  float*  ps    = (float*) (ws + 253755392);
  float*  pq    = (float*) (ws + 253886464);
  float*  sc1   = (float*) (ws + 254017536);
  float*  sh1   = (float*) (ws + 254021632);
  float*  sc2   = (float*) (ws + 254025728);
  float*  sh2   = (float*) (ws + 254029824);
  float*  scd   = (float*) (ws + 254033920);
  float*  shd   = (float*) (ws + 254035968);

  (void)hipFuncSetAttribute((const void*)k_gemmR<0>, hipFuncAttributeMaxDynamicSharedMemorySize, 147456);
  (void)hipFuncSetAttribute((const void*)k_gemmR<2>, hipFuncAttributeMaxDynamicSharedMemorySize, 147456);
  (void)hipFuncSetAttribute((const void*)k_gemmR<3>, hipFuncAttributeMaxDynamicSharedMemorySize, 147456);
  (void)hipFuncSetAttribute((const void*)k_gemmR<4>, hipFuncAttributeMaxDynamicSharedMemorySize, 147456);
  (void)hipFuncSetAttribute((const void*)k_gemmR<5>, hipFuncAttributeMaxDynamicSharedMemorySize, 147456);

  dim3 b256(256), b512(512);
  k_conv<<<dim3(16384), b256, 0, stream>>>(src, src_h, (long)NSRC*QDIM);
  k_prep<<<dim3(9216), b256, 0, stream>>>(Wq, Wv, W1, W2, Wd, WqT, WvT, W1T, W2T, WdT);
  // Q (ring), K and V^T (legacy, fused f32 A)
  k_gemmR<0><<<dim3(256), b512, 147456, stream>>>(src_h, WqT, NSRC, DM, QDIM, bq, nullptr, 1.f, nullptr, Qh, 7, 3);
  k_gemm<0,true><<<dim3(256), b256, 0, stream>>>(a1, WqT, MANC, DM, QDIM, bq, 1.f, nullptr, Kh, 7, 3);
  k_gemm<1,true><<<dim3(256), b256, 0, stream>>>(a2, WvT, MANC, DM, VDIM, bv, 1.f, nullptr, VTh, 7, 3);
  // scores(f16) = (Q K^T)/32 * label_graph ; softmax(f16) ; x = prob V
  k_gemmR<2><<<dim3(1024), b512, 147456, stream>>>(Qh, Kh, NSRC, MANC, DM, nullptr, lg, 0.03125f, nullptr, scores, 31, 5);
  k_softmax<<<dim3(NSRC), b256, 0, stream>>>(scores, prob);
  k_gemmR<3><<<dim3(256), b512, 147456, stream>>>(prob, VTh, NSRC, DM, MANC, nullptr, nullptr, 1.f/512.f, x_att, nullptr, 7, 3);
  // BN1
  k_bn_partial<<<dim3(DM/256, 32), b256, 0, stream>>>(x_att, ps, pq, DM, NSRC/32);
  k_bn_final<<<dim3(DM/256), b256, 0, stream>>>(ps, pq, g1, be1, sc1, sh1, DM, 1.f/NSRC, 32);
  k_bn_apply<<<dim3(8192), b256, 0, stream>>>(x_att, sc1, sh1, xnb, DM, (long)NSRC*DM);
  // FFN
  k_gemmR<4><<<dim3(512), b512, 147456, stream>>>(xnb, W1T, NSRC, FFD, DM, b1, nullptr, 1.f, nullptr, hbuf, 15, 4);
  k_gemmR<5><<<dim3(256), b512, 147456, stream>>>(hbuf, W2T, NSRC, DM, FFD, b2, xnb, 1.f, x2, nullptr, 7, 3);
  // BN2
  k_bn_partial<<<dim3(DM/256, 32), b256, 0, stream>>>(x2, ps, pq, DM, NSRC/32);
  k_bn_final<<<dim3(DM/256), b256, 0, stream>>>(ps, pq, g2, be2, sc2, sh2, DM, 1.f/NSRC, 32);
  k_bn_apply<<<dim3(8192), b256, 0, stream>>>(x2, sc2, sh2, x2nb, DM, (long)NSRC*DM);
  // decoder + BN + tanh
  k_gemm<6,false><<<dim3(256), b256, 0, stream>>>(x2nb, WdT, NSRC, VDIM, DM, bd, 1.f, y, nullptr, 3, 2);
  k_bn_partial<<<dim3(VDIM/256, 32), b256, 0, stream>>>(y, ps, pq, VDIM, NSRC/32);
  k_bn_final<<<dim3(2), b256, 0, stream>>>(ps, pq, gd, bed, scd, shd, VDIM, 1.f/NSRC, 32);
  k_bn_tanh<<<dim3(4096), b256, 0, stream>>>(y, scd, shd, (float*)d_out, VDIM, (long)NSRC*VDIM);
}